// Round 1
// baseline (321.487 us; speedup 1.0000x reference)
//
#include <hip/hip_runtime.h>

typedef unsigned short u16;
typedef __bf16 bf16;
typedef bf16  bf16x8 __attribute__((ext_vector_type(8)));
typedef float f32x4  __attribute__((ext_vector_type(4)));

constexpr int Bc  = 2;
constexpr int Tc  = 2048;
constexpr int Dc  = 1024;
constexpr int Hc  = 16;
constexpr int HDc = 64;
constexpr int Mg  = Bc * Tc;   // 4096 tokens
constexpr int Kg  = Dc;        // 1024 reduction dim

// round-to-nearest-even f32 -> bf16 (finite inputs only)
__device__ inline u16 f2b(float f) {
    union { float f; unsigned u; } c; c.f = f;
    unsigned r = c.u + 0x7FFFu + ((c.u >> 16) & 1u);
    return (u16)(r >> 16);
}

// ---------------- fp32 -> bf16 conversion (vectorized, grid-stride) ----------------
__global__ __launch_bounds__(256) void cvt_kernel(const float* __restrict__ src,
                                                  u16* __restrict__ dst, int n) {
    int i = (blockIdx.x * blockDim.x + threadIdx.x) * 4;
    int stride = gridDim.x * blockDim.x * 4;
    for (; i < n; i += stride) {
        float4 v = *reinterpret_cast<const float4*>(src + i);
        ushort4 o;
        o.x = f2b(v.x); o.y = f2b(v.y); o.z = f2b(v.z); o.w = f2b(v.w);
        *reinterpret_cast<ushort4*>(dst + i) = o;
    }
}

// ---------------- GEMM: C[M,N] = A[M,K] * W[N,K]^T (both bf16, fp32 acc) ----------
// 128x128 tile, BK=32, 256 threads = 4 waves (2x2), each wave 64x64 = 4x4 mfma frags.
// EPI==0: z selects {Q,K,V}; Q/K written [B,H,T,HD] bf16, V written [B,H,HD,T] bf16.
// EPI==1: fp32 out[m*D+n] = acc + bias[n].
template<int EPI>
__global__ __launch_bounds__(256) void gemm_bt(
    const u16* __restrict__ A,
    const u16* __restrict__ W0, const u16* __restrict__ W1, const u16* __restrict__ W2,
    u16* __restrict__ dQ, u16* __restrict__ dK, u16* __restrict__ dV,
    const float* __restrict__ bias, float* __restrict__ outF)
{
    constexpr int LDT = 56;              // padded row stride (112B: 16B-aligned, ~2-way banks)
    __shared__ u16 As[128 * LDT];
    __shared__ u16 Bs[128 * LDT];

    const int t    = threadIdx.x;
    const int z    = blockIdx.z;
    const int m0   = blockIdx.y * 128;
    const int n0   = blockIdx.x * 128;
    const u16* Wsel = (z == 0) ? W0 : (z == 1) ? W1 : W2;

    const int lane = t & 63, wave = t >> 6;
    const int wm = wave >> 1, wn = wave & 1;
    const int lo = lane & 15, hi = lane >> 4;

    f32x4 acc[4][4];
    const f32x4 fzero = {0.f, 0.f, 0.f, 0.f};
    #pragma unroll
    for (int i = 0; i < 4; ++i)
        #pragma unroll
        for (int j = 0; j < 4; ++j) acc[i][j] = fzero;

    const int r0  = t >> 2;         // staging row (0..63), also +64
    const int ko0 = (t & 3) * 8;    // staging k offset within BK

    for (int k0 = 0; k0 < Kg; k0 += 32) {
        __syncthreads();
        *reinterpret_cast<uint4*>(&As[r0 * LDT + ko0]) =
            *reinterpret_cast<const uint4*>(A + (m0 + r0) * Kg + k0 + ko0);
        *reinterpret_cast<uint4*>(&As[(r0 + 64) * LDT + ko0]) =
            *reinterpret_cast<const uint4*>(A + (m0 + r0 + 64) * Kg + k0 + ko0);
        *reinterpret_cast<uint4*>(&Bs[r0 * LDT + ko0]) =
            *reinterpret_cast<const uint4*>(Wsel + (n0 + r0) * Kg + k0 + ko0);
        *reinterpret_cast<uint4*>(&Bs[(r0 + 64) * LDT + ko0]) =
            *reinterpret_cast<const uint4*>(Wsel + (n0 + r0 + 64) * Kg + k0 + ko0);
        __syncthreads();

        bf16x8 af[4], bfr[4];
        #pragma unroll
        for (int fi = 0; fi < 4; ++fi)
            af[fi] = *reinterpret_cast<const bf16x8*>(&As[(wm * 64 + fi * 16 + lo) * LDT + hi * 8]);
        #pragma unroll
        for (int fj = 0; fj < 4; ++fj)
            bfr[fj] = *reinterpret_cast<const bf16x8*>(&Bs[(wn * 64 + fj * 16 + lo) * LDT + hi * 8]);
        #pragma unroll
        for (int fi = 0; fi < 4; ++fi)
            #pragma unroll
            for (int fj = 0; fj < 4; ++fj)
                acc[fi][fj] = __builtin_amdgcn_mfma_f32_16x16x32_bf16(af[fi], bfr[fj], acc[fi][fj], 0, 0, 0);
    }

    // epilogue: C frag layout col=lane&15, row=(lane>>4)*4+reg (HW-verified mapping)
    #pragma unroll
    for (int fi = 0; fi < 4; ++fi) {
        #pragma unroll
        for (int fj = 0; fj < 4; ++fj) {
            const int nn = n0 + wn * 64 + fj * 16 + lo;
            #pragma unroll
            for (int r = 0; r < 4; ++r) {
                const int m = m0 + wm * 64 + fi * 16 + hi * 4 + r;
                float v = acc[fi][fj][r];
                if constexpr (EPI == 0) {
                    const int b = m >> 11, tt = m & (Tc - 1);
                    const int h = nn >> 6, hd = nn & 63;
                    const u16 bv = f2b(v);
                    if (z == 2) {
                        // V transposed: [B,H,HD,T]
                        dV[(((b * Hc + h) * HDc + hd) << 11) + tt] = bv;
                    } else {
                        u16* dst = (z == 0) ? dQ : dK;
                        dst[((((b * Hc + h) << 11) + tt) * HDc) + hd] = bv;
                    }
                } else {
                    outF[m * Dc + nn] = v + bias[nn];
                }
            }
        }
    }
}

// ---------------- causal flash attention ----------------
// 1 wave per (b*h, 16-query tile). K stored [B,H,T,HD] (= B^T frags contiguous in hd),
// V stored [B,H,HD,T] (= B frags contiguous in t). P re-fragmented through padded LDS.
__global__ __launch_bounds__(64) void attn_kernel(const u16* __restrict__ Q,
                                                  const u16* __restrict__ Kk,
                                                  const u16* __restrict__ Vt,
                                                  u16* __restrict__ O)
{
    __shared__ u16 Pl[16 * 56];
    const int lane = threadIdx.x;
    const int lo = lane & 15, hi = lane >> 4;
    const int q0 = blockIdx.x * 16;
    const int bh = blockIdx.y;
    const u16* Qp = Q  + bh * Tc * HDc;
    const u16* Kp = Kk + bh * Tc * HDc;
    const u16* Vp = Vt + bh * HDc * Tc;

    const bf16x8 qf0 = *reinterpret_cast<const bf16x8*>(Qp + (q0 + lo) * HDc + hi * 8);
    const bf16x8 qf1 = *reinterpret_cast<const bf16x8*>(Qp + (q0 + lo) * HDc + 32 + hi * 8);

    f32x4 o[4];
    const f32x4 fzero = {0.f, 0.f, 0.f, 0.f};
    float mr[4], lr[4];
    #pragma unroll
    for (int d = 0; d < 4; ++d) o[d] = fzero;
    #pragma unroll
    for (int r = 0; r < 4; ++r) { mr[r] = -__builtin_inff(); lr[r] = 0.f; }

    const int ntile = (q0 + 47) >> 5;   // causal: keys <= q0+15
    for (int j = 0; j < ntile; ++j) {
        const int kb = j << 5;
        f32x4 s[2];
        #pragma unroll
        for (int cb = 0; cb < 2; ++cb) {
            const u16* kbase = Kp + (kb + cb * 16 + lo) * HDc;
            const bf16x8 kf0 = *reinterpret_cast<const bf16x8*>(kbase + hi * 8);
            const bf16x8 kf1 = *reinterpret_cast<const bf16x8*>(kbase + 32 + hi * 8);
            f32x4 zz = fzero;
            zz    = __builtin_amdgcn_mfma_f32_16x16x32_bf16(qf0, kf0, zz, 0, 0, 0);
            s[cb] = __builtin_amdgcn_mfma_f32_16x16x32_bf16(qf1, kf1, zz, 0, 0, 0);
        }
        float p0[4], p1[4], al[4];
        #pragma unroll
        for (int r = 0; r < 4; ++r) {
            const int q = q0 + hi * 4 + r;
            float v0 = (kb + lo      <= q) ? s[0][r] * 0.125f : -__builtin_inff();
            float v1 = (kb + 16 + lo <= q) ? s[1][r] * 0.125f : -__builtin_inff();
            float tmax = fmaxf(v0, v1);
            tmax = fmaxf(tmax, __shfl_xor(tmax, 1));
            tmax = fmaxf(tmax, __shfl_xor(tmax, 2));
            tmax = fmaxf(tmax, __shfl_xor(tmax, 4));
            tmax = fmaxf(tmax, __shfl_xor(tmax, 8));
            const float mn = fmaxf(mr[r], tmax);   // finite: every row has key 0..kb valid
            const float a  = expf(mr[r] - mn);
            const float e0 = expf(v0 - mn);
            const float e1 = expf(v1 - mn);
            float rs = e0 + e1;
            rs += __shfl_xor(rs, 1);
            rs += __shfl_xor(rs, 2);
            rs += __shfl_xor(rs, 4);
            rs += __shfl_xor(rs, 8);
            lr[r] = lr[r] * a + rs;
            mr[r] = mn;
            p0[r] = e0; p1[r] = e1; al[r] = a;
        }
        #pragma unroll
        for (int d = 0; d < 4; ++d)
            #pragma unroll
            for (int r = 0; r < 4; ++r) o[d][r] *= al[r];

        __syncthreads();
        #pragma unroll
        for (int r = 0; r < 4; ++r) {
            Pl[(hi * 4 + r) * 56 + lo]      = f2b(p0[r]);
            Pl[(hi * 4 + r) * 56 + 16 + lo] = f2b(p1[r]);
        }
        __syncthreads();
        const bf16x8 pa = *reinterpret_cast<const bf16x8*>(&Pl[lo * 56 + hi * 8]);
        #pragma unroll
        for (int d = 0; d < 4; ++d) {
            const bf16x8 vf = *reinterpret_cast<const bf16x8*>(Vp + (d * 16 + lo) * Tc + kb + hi * 8);
            o[d] = __builtin_amdgcn_mfma_f32_16x16x32_bf16(pa, vf, o[d], 0, 0, 0);
        }
    }

    const int b = bh >> 4, h = bh & 15;
    #pragma unroll
    for (int d = 0; d < 4; ++d) {
        #pragma unroll
        for (int r = 0; r < 4; ++r) {
            const int q = q0 + hi * 4 + r;
            O[(b * Tc + q) * Dc + h * 64 + d * 16 + lo] = f2b(o[d][r] / lr[r]);
        }
    }
}

// ---------------- host launcher ----------------
extern "C" void kernel_launch(void* const* d_in, const int* in_sizes, int n_in,
                              void* d_out, int out_size, void* d_ws, size_t ws_size,
                              hipStream_t stream) {
    (void)in_sizes; (void)n_in; (void)out_size; (void)ws_size;
    const float* x  = (const float*)d_in[0];
    const float* Wk = (const float*)d_in[1];
    const float* Wq = (const float*)d_in[2];
    const float* Wv = (const float*)d_in[3];
    const float* Wp = (const float*)d_in[4];
    const float* bp = (const float*)d_in[5];
    float* out = (float*)d_out;

    char* ws = (char*)d_ws;
    // workspace layout (bytes)
    u16* xb   = (u16*)(ws);                         // 4096*1024 bf16 = 8 MB
    u16* wqb  = (u16*)(ws + (8u  << 20));           // 2 MB
    u16* wkb  = (u16*)(ws + (10u << 20));           // 2 MB
    u16* wvb  = (u16*)(ws + (12u << 20));           // 2 MB
    u16* wpb  = (u16*)(ws + (14u << 20));           // 2 MB
    u16* Qb   = (u16*)(ws + (16u << 20));           // [B,H,T,HD] 8 MB
    u16* Kb   = (u16*)(ws + (24u << 20));           // [B,H,T,HD] 8 MB
    u16* Vtb  = (u16*)(ws + (32u << 20));           // [B,H,HD,T] 8 MB
    u16* attb = (u16*)(ws + (40u << 20));           // [B*T, D]   8 MB

    // 1) fp32 -> bf16
    cvt_kernel<<<dim3(512), 256, 0, stream>>>(x,  xb,  Mg * Dc);
    cvt_kernel<<<dim3(256), 256, 0, stream>>>(Wq, wqb, Dc * Dc);
    cvt_kernel<<<dim3(256), 256, 0, stream>>>(Wk, wkb, Dc * Dc);
    cvt_kernel<<<dim3(256), 256, 0, stream>>>(Wv, wvb, Dc * Dc);
    cvt_kernel<<<dim3(256), 256, 0, stream>>>(Wp, wpb, Dc * Dc);

    // 2) QKV GEMMs (z: 0=Q via Wq, 1=K via Wk, 2=V via Wv transposed)
    gemm_bt<0><<<dim3(Dc / 128, Mg / 128, 3), 256, 0, stream>>>(
        xb, wqb, wkb, wvb, Qb, Kb, Vtb, nullptr, nullptr);

    // 3) causal flash attention
    attn_kernel<<<dim3(Tc / 16, Bc * Hc), 64, 0, stream>>>(Qb, Kb, Vtb, attb);

    // 4) output projection + bias -> fp32 d_out
    gemm_bt<1><<<dim3(Dc / 128, Mg / 128, 1), 256, 0, stream>>>(
        attb, wpb, wpb, wpb, nullptr, nullptr, nullptr, bp, out);
}

// Round 2
// 261.635 us; speedup vs baseline: 1.2288x; 1.2288x over previous
//
#include <hip/hip_runtime.h>

typedef unsigned short u16;
typedef __bf16 bf16;
typedef bf16  bf16x8 __attribute__((ext_vector_type(8)));
typedef bf16  bf16x4 __attribute__((ext_vector_type(4)));
typedef float f32x4  __attribute__((ext_vector_type(4)));

constexpr int Bc  = 2;
constexpr int Tc  = 2048;
constexpr int Dc  = 1024;
constexpr int Hc  = 16;
constexpr int HDc = 64;
constexpr int Mg  = Bc * Tc;   // 4096 tokens
constexpr int Kg  = Dc;        // 1024 reduction dim

// round-to-nearest-even f32 -> bf16 (finite inputs only)
__device__ inline u16 f2b(float f) {
    union { float f; unsigned u; } c; c.f = f;
    unsigned r = c.u + 0x7FFFu + ((c.u >> 16) & 1u);
    return (u16)(r >> 16);
}

__device__ inline float exp2_hw(float x) {   // 2^x via v_exp_f32 (handles -inf -> 0)
    float r; asm("v_exp_f32 %0, %1" : "=v"(r) : "v"(x)); return r;
}
__device__ inline unsigned cvt_pk(float a, float b) {  // lo=bf16(a), hi=bf16(b)
    unsigned r; asm("v_cvt_pk_bf16_f32 %0, %1, %2" : "=v"(r) : "v"(a), "v"(b)); return r;
}

// ---------------- fp32 -> bf16 conversion (vectorized, grid-stride) ----------------
__global__ __launch_bounds__(256) void cvt_kernel(const float* __restrict__ src,
                                                  u16* __restrict__ dst, int n) {
    int i = (blockIdx.x * blockDim.x + threadIdx.x) * 4;
    int stride = gridDim.x * blockDim.x * 4;
    for (; i < n; i += stride) {
        float4 v = *reinterpret_cast<const float4*>(src + i);
        ushort4 o;
        o.x = f2b(v.x); o.y = f2b(v.y); o.z = f2b(v.z); o.w = f2b(v.w);
        *reinterpret_cast<ushort4*>(dst + i) = o;
    }
}

// ---------------- GEMM: C[M,N] = A[M,K] * W[N,K]^T (both bf16, fp32 acc) ----------
template<int EPI>
__global__ __launch_bounds__(256) void gemm_bt(
    const u16* __restrict__ A,
    const u16* __restrict__ W0, const u16* __restrict__ W1, const u16* __restrict__ W2,
    u16* __restrict__ dQ, u16* __restrict__ dK, u16* __restrict__ dV,
    const float* __restrict__ bias, float* __restrict__ outF)
{
    constexpr int LDT = 56;
    __shared__ u16 As[128 * LDT];
    __shared__ u16 Bs[128 * LDT];

    const int t    = threadIdx.x;
    const int z    = blockIdx.z;
    const int m0   = blockIdx.y * 128;
    const int n0   = blockIdx.x * 128;
    const u16* Wsel = (z == 0) ? W0 : (z == 1) ? W1 : W2;

    const int lane = t & 63, wave = t >> 6;
    const int wm = wave >> 1, wn = wave & 1;
    const int lo = lane & 15, hi = lane >> 4;

    f32x4 acc[4][4];
    const f32x4 fzero = {0.f, 0.f, 0.f, 0.f};
    #pragma unroll
    for (int i = 0; i < 4; ++i)
        #pragma unroll
        for (int j = 0; j < 4; ++j) acc[i][j] = fzero;

    const int r0  = t >> 2;
    const int ko0 = (t & 3) * 8;

    for (int k0 = 0; k0 < Kg; k0 += 32) {
        __syncthreads();
        *reinterpret_cast<uint4*>(&As[r0 * LDT + ko0]) =
            *reinterpret_cast<const uint4*>(A + (m0 + r0) * Kg + k0 + ko0);
        *reinterpret_cast<uint4*>(&As[(r0 + 64) * LDT + ko0]) =
            *reinterpret_cast<const uint4*>(A + (m0 + r0 + 64) * Kg + k0 + ko0);
        *reinterpret_cast<uint4*>(&Bs[r0 * LDT + ko0]) =
            *reinterpret_cast<const uint4*>(Wsel + (n0 + r0) * Kg + k0 + ko0);
        *reinterpret_cast<uint4*>(&Bs[(r0 + 64) * LDT + ko0]) =
            *reinterpret_cast<const uint4*>(Wsel + (n0 + r0 + 64) * Kg + k0 + ko0);
        __syncthreads();

        bf16x8 af[4], bfr[4];
        #pragma unroll
        for (int fi = 0; fi < 4; ++fi)
            af[fi] = *reinterpret_cast<const bf16x8*>(&As[(wm * 64 + fi * 16 + lo) * LDT + hi * 8]);
        #pragma unroll
        for (int fj = 0; fj < 4; ++fj)
            bfr[fj] = *reinterpret_cast<const bf16x8*>(&Bs[(wn * 64 + fj * 16 + lo) * LDT + hi * 8]);
        #pragma unroll
        for (int fi = 0; fi < 4; ++fi)
            #pragma unroll
            for (int fj = 0; fj < 4; ++fj)
                acc[fi][fj] = __builtin_amdgcn_mfma_f32_16x16x32_bf16(af[fi], bfr[fj], acc[fi][fj], 0, 0, 0);
    }

    #pragma unroll
    for (int fi = 0; fi < 4; ++fi) {
        #pragma unroll
        for (int fj = 0; fj < 4; ++fj) {
            const int nn = n0 + wn * 64 + fj * 16 + lo;
            #pragma unroll
            for (int r = 0; r < 4; ++r) {
                const int m = m0 + wm * 64 + fi * 16 + hi * 4 + r;
                float v = acc[fi][fj][r];
                if constexpr (EPI == 0) {
                    const int b = m >> 11, tt = m & (Tc - 1);
                    const int h = nn >> 6, hd = nn & 63;
                    const u16 bv = f2b(v);
                    if (z == 2) {
                        dV[(((b * Hc + h) * HDc + hd) << 11) + tt] = bv;
                    } else {
                        u16* dst = (z == 0) ? dQ : dK;
                        dst[((((b * Hc + h) << 11) + tt) * HDc) + hd] = bv;
                    }
                } else {
                    outF[m * Dc + nn] = v + bias[nn];
                }
            }
        }
    }
}

// ---------------- causal flash attention, swapped-operand, fully in-register -------
// 1 wave / block; wave = 32 q-rows (2 q-tiles), KVBLK=32 per iter.
// S = mfma(K_frag, Q_frag): lane(lo,hi) holds S[key=kb+16kt+4hi+r][q=qB+16qt+lo].
// P packed in-lane (j=4kt+r) forms a valid A-frag for a k=32 PV mfma, provided V's
// B-frag slot 8hi+j holds V[key=16(j>>2)+4hi+(j&3)] -> two bf16x4 loads from Vt.
__global__ __launch_bounds__(64) void attn_kernel(const u16* __restrict__ Q,
                                                  const u16* __restrict__ Kk,
                                                  const u16* __restrict__ Vt,
                                                  u16* __restrict__ O)
{
    const int lane = threadIdx.x & 63;
    const int lo = lane & 15, hi = lane >> 4;
    const int qB = ((int)gridDim.x - 1 - (int)blockIdx.x) * 32;  // longest blocks first
    const int bh = blockIdx.y;
    const u16* Qp = Q  + bh * Tc * HDc;
    const u16* Kp = Kk + bh * Tc * HDc;
    const u16* Vp = Vt + bh * HDc * Tc;

    const float sc2 = 0.125f * 1.44269504f;   // head-scale * log2(e)

    // Q fragments (B-operand), prescaled so softmax runs in exp2 domain
    bf16x8 qf[2][2];
    #pragma unroll
    for (int qt = 0; qt < 2; ++qt)
        #pragma unroll
        for (int h = 0; h < 2; ++h) {
            union { bf16x8 v; u16 u[8]; } a, r;
            a.v = *reinterpret_cast<const bf16x8*>(Qp + (qB + 16 * qt + lo) * HDc + 32 * h + 8 * hi);
            #pragma unroll
            for (int j = 0; j < 8; ++j) {
                union { float f; unsigned u; } c; c.u = ((unsigned)a.u[j]) << 16;
                r.u[j] = f2b(c.f * sc2);
            }
            qf[qt][h] = r.v;
        }

    f32x4 o[2][4];
    const f32x4 fzero = {0.f, 0.f, 0.f, 0.f};
    #pragma unroll
    for (int qt = 0; qt < 2; ++qt)
        #pragma unroll
        for (int d = 0; d < 4; ++d) o[qt][d] = fzero;
    float mr2[2] = {-__builtin_inff(), -__builtin_inff()};
    float lr[2]  = {0.f, 0.f};

    for (int kb = 0; kb <= qB; kb += 32) {
        // --- K fragments (A-operand): row=key, k=d ---
        const bf16x8 kf00 = *reinterpret_cast<const bf16x8*>(Kp + (kb + lo) * HDc + 8 * hi);
        const bf16x8 kf01 = *reinterpret_cast<const bf16x8*>(Kp + (kb + lo) * HDc + 32 + 8 * hi);
        const bf16x8 kf10 = *reinterpret_cast<const bf16x8*>(Kp + (kb + 16 + lo) * HDc + 8 * hi);
        const bf16x8 kf11 = *reinterpret_cast<const bf16x8*>(Kp + (kb + 16 + lo) * HDc + 32 + 8 * hi);
        // --- V fragments (B-operand, key-permuted to match P's slot order) ---
        bf16x8 vf[4];
        #pragma unroll
        for (int d = 0; d < 4; ++d) {
            union { bf16x8 v; bf16x4 h[2]; } vv;
            const u16* vb = Vp + (16 * d + lo) * Tc + kb + 4 * hi;
            vv.h[0] = *reinterpret_cast<const bf16x4*>(vb);
            vv.h[1] = *reinterpret_cast<const bf16x4*>(vb + 16);
            vf[d] = vv.v;
        }

        // --- S = K·Q^T (swapped): lane holds 8 keys for q=lo ---
        f32x4 s[2][2];
        #pragma unroll
        for (int qt = 0; qt < 2; ++qt) {
            s[qt][0] = __builtin_amdgcn_mfma_f32_16x16x32_bf16(kf00, qf[qt][0], fzero, 0, 0, 0);
            s[qt][0] = __builtin_amdgcn_mfma_f32_16x16x32_bf16(kf01, qf[qt][1], s[qt][0], 0, 0, 0);
            s[qt][1] = __builtin_amdgcn_mfma_f32_16x16x32_bf16(kf10, qf[qt][0], fzero, 0, 0, 0);
            s[qt][1] = __builtin_amdgcn_mfma_f32_16x16x32_bf16(kf11, qf[qt][1], s[qt][1], 0, 0, 0);
        }

        // --- causal mask (only the diagonal tile needs it) ---
        if (kb == qB) {
            #pragma unroll
            for (int qt = 0; qt < 2; ++qt)
                #pragma unroll
                for (int kt = 0; kt < 2; ++kt)
                    #pragma unroll
                    for (int r = 0; r < 4; ++r) {
                        const int key = kb + 16 * kt + 4 * hi + r;
                        const int q   = qB + 16 * qt + lo;
                        if (key > q) s[qt][kt][r] = -__builtin_inff();
                    }
        }

        // --- row max (in-lane 8 + 2 shuffles) ---
        float tm[2];
        #pragma unroll
        for (int qt = 0; qt < 2; ++qt) {
            float m01 = fmaxf(fmaxf(s[qt][0][0], s[qt][0][1]), fmaxf(s[qt][0][2], s[qt][0][3]));
            float m23 = fmaxf(fmaxf(s[qt][1][0], s[qt][1][1]), fmaxf(s[qt][1][2], s[qt][1][3]));
            float t = fmaxf(m01, m23);
            t = fmaxf(t, __shfl_xor(t, 16));
            t = fmaxf(t, __shfl_xor(t, 32));
            tm[qt] = t;
        }

        // --- defer-max: skip o-rescale unless max grew notably (T13) ---
        const bool deferOK = (tm[0] <= mr2[0] + 11.5f) && (tm[1] <= mr2[1] + 11.5f);
        if (!__all(deferOK)) {
            #pragma unroll
            for (int qt = 0; qt < 2; ++qt) {
                const float mn = fmaxf(mr2[qt], tm[qt]);
                const float aq = exp2_hw(mr2[qt] - mn);   // -inf -> 0 on first tile
                mr2[qt] = mn;
                lr[qt] *= aq;
                float ar[4];
                #pragma unroll
                for (int r = 0; r < 4; ++r) ar[r] = __shfl(aq, 4 * hi + r);
                #pragma unroll
                for (int d = 0; d < 4; ++d)
                    #pragma unroll
                    for (int r = 0; r < 4; ++r) o[qt][d][r] *= ar[r];
            }
        }

        // --- P = exp2(S - m), row-sum, pack to bf16 A-frags ---
        bf16x8 pa[2];
        #pragma unroll
        for (int qt = 0; qt < 2; ++qt) {
            float p[8];
            #pragma unroll
            for (int kt = 0; kt < 2; ++kt)
                #pragma unroll
                for (int r = 0; r < 4; ++r)
                    p[4 * kt + r] = exp2_hw(s[qt][kt][r] - mr2[qt]);
            float ts = ((p[0] + p[1]) + (p[2] + p[3])) + ((p[4] + p[5]) + (p[6] + p[7]));
            ts += __shfl_xor(ts, 16);
            ts += __shfl_xor(ts, 32);
            lr[qt] += ts;
            union { bf16x8 v; unsigned w[4]; } pk;
            pk.w[0] = cvt_pk(p[0], p[1]);
            pk.w[1] = cvt_pk(p[2], p[3]);
            pk.w[2] = cvt_pk(p[4], p[5]);
            pk.w[3] = cvt_pk(p[6], p[7]);
            pa[qt] = pk.v;
        }

        // --- PV ---
        #pragma unroll
        for (int qt = 0; qt < 2; ++qt)
            #pragma unroll
            for (int d = 0; d < 4; ++d)
                o[qt][d] = __builtin_amdgcn_mfma_f32_16x16x32_bf16(pa[qt], vf[d], o[qt][d], 0, 0, 0);
    }

    // --- epilogue: transpose 1/l to row domain, write out ---
    const int b = bh >> 4, h = bh & 15;
    #pragma unroll
    for (int qt = 0; qt < 2; ++qt) {
        float li[4];
        #pragma unroll
        for (int r = 0; r < 4; ++r) li[r] = 1.0f / __shfl(lr[qt], 4 * hi + r);
        #pragma unroll
        for (int d = 0; d < 4; ++d)
            #pragma unroll
            for (int r = 0; r < 4; ++r) {
                const int q = qB + 16 * qt + 4 * hi + r;
                O[(b * Tc + q) * Dc + h * 64 + 16 * d + lo] = f2b(o[qt][d][r] * li[r]);
            }
    }
}

// ---------------- host launcher ----------------
extern "C" void kernel_launch(void* const* d_in, const int* in_sizes, int n_in,
                              void* d_out, int out_size, void* d_ws, size_t ws_size,
                              hipStream_t stream) {
    (void)in_sizes; (void)n_in; (void)out_size; (void)ws_size;
    const float* x  = (const float*)d_in[0];
    const float* Wk = (const float*)d_in[1];
    const float* Wq = (const float*)d_in[2];
    const float* Wv = (const float*)d_in[3];
    const float* Wp = (const float*)d_in[4];
    const float* bp = (const float*)d_in[5];
    float* out = (float*)d_out;

    char* ws = (char*)d_ws;
    u16* xb   = (u16*)(ws);
    u16* wqb  = (u16*)(ws + (8u  << 20));
    u16* wkb  = (u16*)(ws + (10u << 20));
    u16* wvb  = (u16*)(ws + (12u << 20));
    u16* wpb  = (u16*)(ws + (14u << 20));
    u16* Qb   = (u16*)(ws + (16u << 20));
    u16* Kb   = (u16*)(ws + (24u << 20));
    u16* Vtb  = (u16*)(ws + (32u << 20));
    u16* attb = (u16*)(ws + (40u << 20));

    cvt_kernel<<<dim3(512), 256, 0, stream>>>(x,  xb,  Mg * Dc);
    cvt_kernel<<<dim3(256), 256, 0, stream>>>(Wq, wqb, Dc * Dc);
    cvt_kernel<<<dim3(256), 256, 0, stream>>>(Wk, wkb, Dc * Dc);
    cvt_kernel<<<dim3(256), 256, 0, stream>>>(Wv, wvb, Dc * Dc);
    cvt_kernel<<<dim3(256), 256, 0, stream>>>(Wp, wpb, Dc * Dc);

    gemm_bt<0><<<dim3(Dc / 128, Mg / 128, 3), 256, 0, stream>>>(
        xb, wqb, wkb, wvb, Qb, Kb, Vtb, nullptr, nullptr);

    attn_kernel<<<dim3(Tc / 32, Bc * Hc), 64, 0, stream>>>(Qb, Kb, Vtb, attb);

    gemm_bt<1><<<dim3(Dc / 128, Mg / 128, 1), 256, 0, stream>>>(
        attb, wpb, wpb, wpb, nullptr, nullptr, nullptr, bp, out);
}

// Round 3
// 259.413 us; speedup vs baseline: 1.2393x; 1.0086x over previous
//
#include <hip/hip_runtime.h>

typedef unsigned short u16;
typedef __bf16 bf16;
typedef bf16  bf16x8 __attribute__((ext_vector_type(8)));
typedef bf16  bf16x4 __attribute__((ext_vector_type(4)));
typedef float f32x4  __attribute__((ext_vector_type(4)));

constexpr int Bc  = 2;
constexpr int Tc  = 2048;
constexpr int Dc  = 1024;
constexpr int Hc  = 16;
constexpr int HDc = 64;
constexpr int Mg  = Bc * Tc;   // 4096 tokens
constexpr int Kg  = Dc;        // 1024 reduction dim

// round-to-nearest-even f32 -> bf16 (finite inputs only)
__device__ inline u16 f2b(float f) {
    union { float f; unsigned u; } c; c.f = f;
    unsigned r = c.u + 0x7FFFu + ((c.u >> 16) & 1u);
    return (u16)(r >> 16);
}

__device__ inline float exp2_hw(float x) {
    float r; asm("v_exp_f32 %0, %1" : "=v"(r) : "v"(x)); return r;
}
__device__ inline unsigned cvt_pk(float a, float b) {
    unsigned r; asm("v_cvt_pk_bf16_f32 %0, %1, %2" : "=v"(r) : "v"(a), "v"(b)); return r;
}
__device__ inline void gload16(const u16* g, u16* l) {
    __builtin_amdgcn_global_load_lds(
        (const __attribute__((address_space(1))) void*)g,
        (__attribute__((address_space(3))) void*)l, 16, 0, 0);
}

// ---------------- fused fp32 -> bf16 conversion (all 5 tensors, 1 launch) --------
struct CvtArgs { const float* src[5]; u16* dst[5]; int n[5]; };

__global__ __launch_bounds__(256) void cvt_all(CvtArgs a) {
    const int tid = blockIdx.x * blockDim.x + threadIdx.x;
    const int stride = gridDim.x * blockDim.x * 4;
    #pragma unroll
    for (int r = 0; r < 5; ++r) {
        const float* s = a.src[r];
        u16* d = a.dst[r];
        const int n = a.n[r];
        for (int i = tid * 4; i < n; i += stride) {
            float4 v = *reinterpret_cast<const float4*>(s + i);
            ushort4 o;
            o.x = f2b(v.x); o.y = f2b(v.y); o.z = f2b(v.z); o.w = f2b(v.w);
            *reinterpret_cast<ushort4*>(d + i) = o;
        }
    }
}

// ---------------- GEMM: C[M,N] = A[M,K] * W[N,K]^T (m97 structure) ----------------
// 128x128 tile, BK=32, 4 waves. global_load_lds width=16 into LINEAR LDS [128][32],
// k-slot XOR-swizzled on the GLOBAL side (slot' = slot ^ (row&3)) and on the
// ds_read side -> 2-way (free) bank conflicts on the stride-64B fragment reads.
template<int EPI>
__global__ __launch_bounds__(256) void gemm_bt(
    const u16* __restrict__ A,
    const u16* __restrict__ W0, const u16* __restrict__ W1, const u16* __restrict__ W2,
    u16* __restrict__ dQ, u16* __restrict__ dK, u16* __restrict__ dV,
    const float* __restrict__ bias, float* __restrict__ outF)
{
    __shared__ u16 As[128 * 32];
    __shared__ u16 Bs[128 * 32];

    const int t    = threadIdx.x;
    const int z    = blockIdx.z;
    const int m0   = blockIdx.y * 128;
    const int n0   = blockIdx.x * 128;
    const u16* Wsel = (z == 0) ? W0 : (z == 1) ? W1 : W2;

    const int lane = t & 63, wave = t >> 6;
    const int wm = wave >> 1, wn = wave & 1;
    const int lo = lane & 15, hi = lane >> 4;

    f32x4 acc[4][4];
    const f32x4 fzero = {0.f, 0.f, 0.f, 0.f};
    #pragma unroll
    for (int i = 0; i < 4; ++i)
        #pragma unroll
        for (int j = 0; j < 4; ++j) acc[i][j] = fzero;

    // staging: lane writes LDS row rA=t>>2, physical slot t&3; fetch k-slot (t&3)^(rA&3)
    const int rA = t >> 2;
    const int ks = ((t & 3) ^ (rA & 3)) * 8;
    const u16* gA0 = A    + (size_t)(m0 + rA) * Kg + ks;
    const u16* gA1 = gA0 + 64 * Kg;
    const u16* gB0 = Wsel + (size_t)(n0 + rA) * Kg + ks;
    const u16* gB1 = gB0 + 64 * Kg;
    u16* lA0 = &As[(wave * 16) * 32];        // wave-uniform LDS bases
    u16* lA1 = &As[(64 + wave * 16) * 32];
    u16* lB0 = &Bs[(wave * 16) * 32];
    u16* lB1 = &Bs[(64 + wave * 16) * 32];

    const int sl = (hi ^ (lo & 3)) * 8;      // swizzled read slot (row&3 == lo&3)

    for (int k0 = 0; k0 < Kg; k0 += 32) {
        __syncthreads();
        gload16(gA0 + k0, lA0);
        gload16(gA1 + k0, lA1);
        gload16(gB0 + k0, lB0);
        gload16(gB1 + k0, lB1);
        __syncthreads();

        bf16x8 af[4], bfr[4];
        #pragma unroll
        for (int fi = 0; fi < 4; ++fi)
            af[fi] = *reinterpret_cast<const bf16x8*>(&As[(wm * 64 + fi * 16 + lo) * 32 + sl]);
        #pragma unroll
        for (int fj = 0; fj < 4; ++fj)
            bfr[fj] = *reinterpret_cast<const bf16x8*>(&Bs[(wn * 64 + fj * 16 + lo) * 32 + sl]);
        #pragma unroll
        for (int fi = 0; fi < 4; ++fi)
            #pragma unroll
            for (int fj = 0; fj < 4; ++fj)
                acc[fi][fj] = __builtin_amdgcn_mfma_f32_16x16x32_bf16(af[fi], bfr[fj], acc[fi][fj], 0, 0, 0);
    }

    // epilogue: C frag layout col=lane&15, row=(lane>>4)*4+reg
    #pragma unroll
    for (int fi = 0; fi < 4; ++fi) {
        #pragma unroll
        for (int fj = 0; fj < 4; ++fj) {
            const int nn = n0 + wn * 64 + fj * 16 + lo;
            if constexpr (EPI == 0) {
                const int b = m0 >> 11;
                const int h = nn >> 6, hd = nn & 63;
                if (z == 2) {
                    // V transposed [B,H,HD,T]: r gives consecutive t -> packed store
                    const int tt0 = (m0 & (Tc - 1)) + wm * 64 + fi * 16 + hi * 4;
                    ushort4 pv;
                    pv.x = f2b(acc[fi][fj][0]); pv.y = f2b(acc[fi][fj][1]);
                    pv.z = f2b(acc[fi][fj][2]); pv.w = f2b(acc[fi][fj][3]);
                    *reinterpret_cast<ushort4*>(&dV[(((b * Hc + h) * HDc + hd) << 11) + tt0]) = pv;
                } else {
                    u16* dst = (z == 0) ? dQ : dK;
                    #pragma unroll
                    for (int r = 0; r < 4; ++r) {
                        const int m = m0 + wm * 64 + fi * 16 + hi * 4 + r;
                        const int tt = m & (Tc - 1);
                        dst[((((b * Hc + h) << 11) + tt) * HDc) + hd] = f2b(acc[fi][fj][r]);
                    }
                }
            } else {
                #pragma unroll
                for (int r = 0; r < 4; ++r) {
                    const int m = m0 + wm * 64 + fi * 16 + hi * 4 + r;
                    outF[(size_t)m * Dc + nn] = acc[fi][fj][r] + bias[nn];
                }
            }
        }
    }
}

// ---------------- causal flash attention, paired q-tiles + prefetch ---------------
// 1 wave / block. Block pi owns 16-row q-tiles {pi, 127-pi} of its (b,h): total key
// work is constant across blocks (triangle pairing) -> zero drain tail. Both tiles
// consume the SAME K/V stream; next k-tile's K/V prefetched into regs (1-deep pipe).
__global__ __launch_bounds__(64) void attn_kernel(const u16* __restrict__ Q,
                                                  const u16* __restrict__ Kk,
                                                  const u16* __restrict__ Vt,
                                                  u16* __restrict__ O)
{
    const int lane = threadIdx.x & 63;
    const int lo = lane & 15, hi = lane >> 4;
    const int pi = blockIdx.x;                     // 0..63
    const int bh = blockIdx.y;
    const int q0a = 16 * pi;                       // small tile
    const int q0b = 16 * (127 - pi);               // large tile
    const u16* Qp = Q  + bh * Tc * HDc;
    const u16* Kp = Kk + bh * Tc * HDc;
    const u16* Vp = Vt + bh * HDc * Tc;

    const float sc2 = 0.125f * 1.44269504f;        // head-scale * log2(e)

    bf16x8 qfa[2], qfb[2];
    #pragma unroll
    for (int h = 0; h < 2; ++h) {
        union { bf16x8 v; u16 u[8]; } a, r;
        a.v = *reinterpret_cast<const bf16x8*>(Qp + (q0a + lo) * HDc + 32 * h + 8 * hi);
        #pragma unroll
        for (int j = 0; j < 8; ++j) {
            union { float f; unsigned u; } c; c.u = ((unsigned)a.u[j]) << 16;
            r.u[j] = f2b(c.f * sc2);
        }
        qfa[h] = r.v;
        a.v = *reinterpret_cast<const bf16x8*>(Qp + (q0b + lo) * HDc + 32 * h + 8 * hi);
        #pragma unroll
        for (int j = 0; j < 8; ++j) {
            union { float f; unsigned u; } c; c.u = ((unsigned)a.u[j]) << 16;
            r.u[j] = f2b(c.f * sc2);
        }
        qfb[h] = r.v;
    }

    f32x4 oa[4], ob[4];
    const f32x4 fzero = {0.f, 0.f, 0.f, 0.f};
    #pragma unroll
    for (int d = 0; d < 4; ++d) { oa[d] = fzero; ob[d] = fzero; }
    float ma = -__builtin_inff(), mb = -__builtin_inff();
    float la = 0.f, lb = 0.f;

    bf16x8 kc[4], vc[4];
    auto loadKV = [&](int kb, bf16x8* k, bf16x8* v) {
        k[0] = *reinterpret_cast<const bf16x8*>(Kp + (kb + lo) * HDc + 8 * hi);
        k[1] = *reinterpret_cast<const bf16x8*>(Kp + (kb + lo) * HDc + 32 + 8 * hi);
        k[2] = *reinterpret_cast<const bf16x8*>(Kp + (kb + 16 + lo) * HDc + 8 * hi);
        k[3] = *reinterpret_cast<const bf16x8*>(Kp + (kb + 16 + lo) * HDc + 32 + 8 * hi);
        #pragma unroll
        for (int d = 0; d < 4; ++d) {
            union { bf16x8 w; bf16x4 h2[2]; } vv;
            const u16* vb = Vp + (16 * d + lo) * Tc + kb + 4 * hi;
            vv.h2[0] = *reinterpret_cast<const bf16x4*>(vb);
            vv.h2[1] = *reinterpret_cast<const bf16x4*>(vb + 16);
            v[d] = vv.w;
        }
    };

    auto step = [&](int q0v, const bf16x8 (&qv)[2], f32x4 (&ov)[4],
                    float& m2, float& l2, int kb) {
        f32x4 s0, s1;
        s0 = __builtin_amdgcn_mfma_f32_16x16x32_bf16(kc[0], qv[0], fzero, 0, 0, 0);
        s0 = __builtin_amdgcn_mfma_f32_16x16x32_bf16(kc[1], qv[1], s0, 0, 0, 0);
        s1 = __builtin_amdgcn_mfma_f32_16x16x32_bf16(kc[2], qv[0], fzero, 0, 0, 0);
        s1 = __builtin_amdgcn_mfma_f32_16x16x32_bf16(kc[3], qv[1], s1, 0, 0, 0);

        if (kb + 31 > q0v) {   // diagonal: mask keys > q
            const int q = q0v + lo;
            #pragma unroll
            for (int r = 0; r < 4; ++r) {
                if (kb + 4 * hi + r > q)      s0[r] = -__builtin_inff();
                if (kb + 16 + 4 * hi + r > q) s1[r] = -__builtin_inff();
            }
        }

        float tm = fmaxf(fmaxf(fmaxf(s0[0], s0[1]), fmaxf(s0[2], s0[3])),
                         fmaxf(fmaxf(s1[0], s1[1]), fmaxf(s1[2], s1[3])));
        tm = fmaxf(tm, __shfl_xor(tm, 16));
        tm = fmaxf(tm, __shfl_xor(tm, 32));

        if (!__all(tm <= m2 + 11.5f)) {        // defer-max (T13)
            const float mn = fmaxf(m2, tm);
            const float aq = exp2_hw(m2 - mn); // -inf -> 0 on first tile
            m2 = mn;
            l2 *= aq;
            float ar[4];
            #pragma unroll
            for (int r = 0; r < 4; ++r) ar[r] = __shfl(aq, 4 * hi + r);
            #pragma unroll
            for (int d = 0; d < 4; ++d)
                #pragma unroll
                for (int r = 0; r < 4; ++r) ov[d][r] *= ar[r];
        }

        float p[8];
        #pragma unroll
        for (int r = 0; r < 4; ++r) p[r]     = exp2_hw(s0[r] - m2);
        #pragma unroll
        for (int r = 0; r < 4; ++r) p[4 + r] = exp2_hw(s1[r] - m2);
        float ts = ((p[0] + p[1]) + (p[2] + p[3])) + ((p[4] + p[5]) + (p[6] + p[7]));
        ts += __shfl_xor(ts, 16);
        ts += __shfl_xor(ts, 32);
        l2 += ts;
        union { bf16x8 v; unsigned w[4]; } pk;
        pk.w[0] = cvt_pk(p[0], p[1]);
        pk.w[1] = cvt_pk(p[2], p[3]);
        pk.w[2] = cvt_pk(p[4], p[5]);
        pk.w[3] = cvt_pk(p[6], p[7]);
        #pragma unroll
        for (int d = 0; d < 4; ++d)
            ov[d] = __builtin_amdgcn_mfma_f32_16x16x32_bf16(pk.v, vc[d], ov[d], 0, 0, 0);
    };

    loadKV(0, kc, vc);
    const int kbLast = ((q0b + 15) >> 5) << 5;
    for (int kb = 0; ; kb += 32) {
        bf16x8 kn[4], vn[4];
        const bool notLast = (kb < kbLast);
        if (notLast) loadKV(kb + 32, kn, vn);

        step(q0b, qfb, ob, mb, lb, kb);
        if (kb <= q0a + 15) step(q0a, qfa, oa, ma, la, kb);

        if (!notLast) break;
        #pragma unroll
        for (int j = 0; j < 4; ++j) { kc[j] = kn[j]; vc[j] = vn[j]; }
    }

    // epilogue
    const int b = bh >> 4, h = bh & 15;
    {
        float li[4];
        #pragma unroll
        for (int r = 0; r < 4; ++r) li[r] = 1.0f / __shfl(la, 4 * hi + r);
        #pragma unroll
        for (int d = 0; d < 4; ++d)
            #pragma unroll
            for (int r = 0; r < 4; ++r) {
                const int q = q0a + 4 * hi + r;
                O[(size_t)(b * Tc + q) * Dc + h * 64 + 16 * d + lo] = f2b(oa[d][r] * li[r]);
            }
        #pragma unroll
        for (int r = 0; r < 4; ++r) li[r] = 1.0f / __shfl(lb, 4 * hi + r);
        #pragma unroll
        for (int d = 0; d < 4; ++d)
            #pragma unroll
            for (int r = 0; r < 4; ++r) {
                const int q = q0b + 4 * hi + r;
                O[(size_t)(b * Tc + q) * Dc + h * 64 + 16 * d + lo] = f2b(ob[d][r] * li[r]);
            }
    }
}

// ---------------- host launcher ----------------
extern "C" void kernel_launch(void* const* d_in, const int* in_sizes, int n_in,
                              void* d_out, int out_size, void* d_ws, size_t ws_size,
                              hipStream_t stream) {
    (void)in_sizes; (void)n_in; (void)out_size; (void)ws_size;
    const float* x  = (const float*)d_in[0];
    const float* Wk = (const float*)d_in[1];
    const float* Wq = (const float*)d_in[2];
    const float* Wv = (const float*)d_in[3];
    const float* Wp = (const float*)d_in[4];
    const float* bp = (const float*)d_in[5];
    float* out = (float*)d_out;

    char* ws = (char*)d_ws;
    u16* xb   = (u16*)(ws);
    u16* wqb  = (u16*)(ws + (8u  << 20));
    u16* wkb  = (u16*)(ws + (10u << 20));
    u16* wvb  = (u16*)(ws + (12u << 20));
    u16* wpb  = (u16*)(ws + (14u << 20));
    u16* Qb   = (u16*)(ws + (16u << 20));
    u16* Kb   = (u16*)(ws + (24u << 20));
    u16* Vtb  = (u16*)(ws + (32u << 20));
    u16* attb = (u16*)(ws + (40u << 20));

    CvtArgs ca;
    ca.src[0] = x;  ca.dst[0] = xb;  ca.n[0] = Mg * Dc;
    ca.src[1] = Wq; ca.dst[1] = wqb; ca.n[1] = Dc * Dc;
    ca.src[2] = Wk; ca.dst[2] = wkb; ca.n[2] = Dc * Dc;
    ca.src[3] = Wv; ca.dst[3] = wvb; ca.n[3] = Dc * Dc;
    ca.src[4] = Wp; ca.dst[4] = wpb; ca.n[4] = Dc * Dc;
    cvt_all<<<dim3(1024), 256, 0, stream>>>(ca);

    gemm_bt<0><<<dim3(Dc / 128, Mg / 128, 3), 256, 0, stream>>>(
        xb, wqb, wkb, wvb, Qb, Kb, Vtb, nullptr, nullptr);

    attn_kernel<<<dim3(64, Bc * Hc), 64, 0, stream>>>(Qb, Kb, Vtb, attb);

    gemm_bt<1><<<dim3(Dc / 128, Mg / 128, 1), 256, 0, stream>>>(
        attb, wpb, wpb, wpb, nullptr, nullptr, nullptr, bp, out);
}

// Round 4
// 236.837 us; speedup vs baseline: 1.3574x; 1.0953x over previous
//
#include <hip/hip_runtime.h>

typedef unsigned short u16;
typedef __bf16 bf16;
typedef bf16  bf16x8 __attribute__((ext_vector_type(8)));
typedef bf16  bf16x4 __attribute__((ext_vector_type(4)));
typedef float f32x4  __attribute__((ext_vector_type(4)));

constexpr int Bc  = 2;
constexpr int Tc  = 2048;
constexpr int Dc  = 1024;
constexpr int Hc  = 16;
constexpr int HDc = 64;
constexpr int Mg  = Bc * Tc;   // 4096 tokens
constexpr int Kg  = Dc;        // 1024 reduction dim

// round-to-nearest-even f32 -> bf16 (finite inputs only)
__device__ inline u16 f2b(float f) {
    union { float f; unsigned u; } c; c.f = f;
    unsigned r = c.u + 0x7FFFu + ((c.u >> 16) & 1u);
    return (u16)(r >> 16);
}

__device__ inline float exp2_hw(float x) {
    float r; asm("v_exp_f32 %0, %1" : "=v"(r) : "v"(x)); return r;
}
__device__ inline unsigned cvt_pk(float a, float b) {
    unsigned r; asm("v_cvt_pk_bf16_f32 %0, %1, %2" : "=v"(r) : "v"(a), "v"(b)); return r;
}
__device__ inline void gload16(const u16* g, u16* l) {
    __builtin_amdgcn_global_load_lds(
        (const __attribute__((address_space(1))) void*)g,
        (__attribute__((address_space(3))) void*)l, 16, 0, 0);
}

// ---------------- fused fp32 -> bf16 conversion (all 5 tensors, 1 launch) --------
struct CvtArgs { const float* src[5]; u16* dst[5]; int n[5]; };

__global__ __launch_bounds__(256) void cvt_all(CvtArgs a) {
    const int tid = blockIdx.x * blockDim.x + threadIdx.x;
    const int stride = gridDim.x * blockDim.x * 4;
    #pragma unroll
    for (int r = 0; r < 5; ++r) {
        const float* s = a.src[r];
        u16* d = a.dst[r];
        const int n = a.n[r];
        for (int i = tid * 4; i < n; i += stride) {
            float4 v = *reinterpret_cast<const float4*>(s + i);
            ushort4 o;
            o.x = f2b(v.x); o.y = f2b(v.y); o.z = f2b(v.z); o.w = f2b(v.w);
            *reinterpret_cast<ushort4*>(d + i) = o;
        }
    }
}

// ---------------- GEMM: C[M,N] = A[M,K] * W[N,K]^T (m97 structure) ----------------
template<int EPI>
__global__ __launch_bounds__(256) void gemm_bt(
    const u16* __restrict__ A,
    const u16* __restrict__ W0, const u16* __restrict__ W1, const u16* __restrict__ W2,
    u16* __restrict__ dQ, u16* __restrict__ dK, u16* __restrict__ dV,
    const float* __restrict__ bias, float* __restrict__ outF)
{
    __shared__ u16 As[128 * 32];
    __shared__ u16 Bs[128 * 32];

    const int t    = threadIdx.x;
    const int z    = blockIdx.z;
    const int m0   = blockIdx.y * 128;
    const int n0   = blockIdx.x * 128;
    const u16* Wsel = (z == 0) ? W0 : (z == 1) ? W1 : W2;

    const int lane = t & 63, wave = t >> 6;
    const int wm = wave >> 1, wn = wave & 1;
    const int lo = lane & 15, hi = lane >> 4;

    f32x4 acc[4][4];
    const f32x4 fzero = {0.f, 0.f, 0.f, 0.f};
    #pragma unroll
    for (int i = 0; i < 4; ++i)
        #pragma unroll
        for (int j = 0; j < 4; ++j) acc[i][j] = fzero;

    const int rA = t >> 2;
    const int ks = ((t & 3) ^ (rA & 3)) * 8;
    const u16* gA0 = A    + (size_t)(m0 + rA) * Kg + ks;
    const u16* gA1 = gA0 + 64 * Kg;
    const u16* gB0 = Wsel + (size_t)(n0 + rA) * Kg + ks;
    const u16* gB1 = gB0 + 64 * Kg;
    u16* lA0 = &As[(wave * 16) * 32];
    u16* lA1 = &As[(64 + wave * 16) * 32];
    u16* lB0 = &Bs[(wave * 16) * 32];
    u16* lB1 = &Bs[(64 + wave * 16) * 32];

    const int sl = (hi ^ (lo & 3)) * 8;

    for (int k0 = 0; k0 < Kg; k0 += 32) {
        __syncthreads();
        gload16(gA0 + k0, lA0);
        gload16(gA1 + k0, lA1);
        gload16(gB0 + k0, lB0);
        gload16(gB1 + k0, lB1);
        __syncthreads();

        bf16x8 af[4], bfr[4];
        #pragma unroll
        for (int fi = 0; fi < 4; ++fi)
            af[fi] = *reinterpret_cast<const bf16x8*>(&As[(wm * 64 + fi * 16 + lo) * 32 + sl]);
        #pragma unroll
        for (int fj = 0; fj < 4; ++fj)
            bfr[fj] = *reinterpret_cast<const bf16x8*>(&Bs[(wn * 64 + fj * 16 + lo) * 32 + sl]);
        #pragma unroll
        for (int fi = 0; fi < 4; ++fi)
            #pragma unroll
            for (int fj = 0; fj < 4; ++fj)
                acc[fi][fj] = __builtin_amdgcn_mfma_f32_16x16x32_bf16(af[fi], bfr[fj], acc[fi][fj], 0, 0, 0);
    }

    #pragma unroll
    for (int fi = 0; fi < 4; ++fi) {
        #pragma unroll
        for (int fj = 0; fj < 4; ++fj) {
            const int nn = n0 + wn * 64 + fj * 16 + lo;
            if constexpr (EPI == 0) {
                const int b = m0 >> 11;
                const int h = nn >> 6, hd = nn & 63;
                if (z == 2) {
                    const int tt0 = (m0 & (Tc - 1)) + wm * 64 + fi * 16 + hi * 4;
                    ushort4 pv;
                    pv.x = f2b(acc[fi][fj][0]); pv.y = f2b(acc[fi][fj][1]);
                    pv.z = f2b(acc[fi][fj][2]); pv.w = f2b(acc[fi][fj][3]);
                    *reinterpret_cast<ushort4*>(&dV[(((b * Hc + h) * HDc + hd) << 11) + tt0]) = pv;
                } else {
                    u16* dst = (z == 0) ? dQ : dK;
                    #pragma unroll
                    for (int r = 0; r < 4; ++r) {
                        const int m = m0 + wm * 64 + fi * 16 + hi * 4 + r;
                        const int tt = m & (Tc - 1);
                        dst[((((b * Hc + h) << 11) + tt) * HDc) + hd] = f2b(acc[fi][fj][r]);
                    }
                }
            } else {
                #pragma unroll
                for (int r = 0; r < 4; ++r) {
                    const int m = m0 + wm * 64 + fi * 16 + hi * 4 + r;
                    outF[(size_t)m * Dc + nn] = acc[fi][fj][r] + bias[nn];
                }
            }
        }
    }
}

// ---------------- causal flash attention: 4 key-split waves + LDS merge ----------
// Block = (q-chunk of 32 rows) x (b,h). Wave w sweeps keys [w*span, min(..,range)).
// Each wave: in-register swapped-operand online softmax (S = mfma(K,Q), q = lane&15).
// Waves 1-3 dump unnormalized (m,l,o) to LDS; wave 0 merges and writes O.
__global__ __launch_bounds__(256) void attn_kernel(const u16* __restrict__ Q,
                                                   const u16* __restrict__ Kk,
                                                   const u16* __restrict__ Vt,
                                                   u16* __restrict__ O)
{
    __shared__ float oS[3][32][65];   // padded: bank = (row*65+col)&31 varies with row
    __shared__ float mS[3][32];
    __shared__ float lS[3][32];

    const int t = threadIdx.x;
    const int w = t >> 6;                               // key-split index 0..3
    const int lane = t & 63;
    const int lo = lane & 15, hi = lane >> 4;
    const int qc = (int)gridDim.x - 1 - (int)blockIdx.x; // longest chunks first
    const int qB = qc * 32;
    const int bh = blockIdx.y;
    const int range = qB + 32;                          // causal key count
    const int span  = ((8 * (qc + 1) + 31) >> 5) << 5;  // per-wave key span (mult of 32)
    const int k0    = w * span;
    const int kEnd  = min(k0 + span, range);
    const bool active = k0 < kEnd;

    const u16* Qp = Q  + bh * Tc * HDc;
    const u16* Kp = Kk + bh * Tc * HDc;
    const u16* Vp = Vt + bh * HDc * Tc;

    const float sc2 = 0.125f * 1.44269504f;             // head-scale * log2(e)
    const f32x4 fzero = {0.f, 0.f, 0.f, 0.f};

    f32x4 o[2][4];
    float m2[2] = {-__builtin_inff(), -__builtin_inff()};
    float l2[2] = {0.f, 0.f};
    #pragma unroll
    for (int qt = 0; qt < 2; ++qt)
        #pragma unroll
        for (int d = 0; d < 4; ++d) o[qt][d] = fzero;

    if (active) {
        // Q fragments (B-operand), prescaled into exp2 domain
        bf16x8 qf[2][2];
        #pragma unroll
        for (int qt = 0; qt < 2; ++qt)
            #pragma unroll
            for (int h = 0; h < 2; ++h) {
                union { bf16x8 v; u16 u[8]; } a2, r2;
                a2.v = *reinterpret_cast<const bf16x8*>(Qp + (qB + 16 * qt + lo) * HDc + 32 * h + 8 * hi);
                #pragma unroll
                for (int j = 0; j < 8; ++j) {
                    union { float f; unsigned u; } c; c.u = ((unsigned)a2.u[j]) << 16;
                    r2.u[j] = f2b(c.f * sc2);
                }
                qf[qt][h] = r2.v;
            }

        bf16x8 kc[4];
        auto loadK = [&](int kb, bf16x8* k) {
            k[0] = *reinterpret_cast<const bf16x8*>(Kp + (kb + lo) * HDc + 8 * hi);
            k[1] = *reinterpret_cast<const bf16x8*>(Kp + (kb + lo) * HDc + 32 + 8 * hi);
            k[2] = *reinterpret_cast<const bf16x8*>(Kp + (kb + 16 + lo) * HDc + 8 * hi);
            k[3] = *reinterpret_cast<const bf16x8*>(Kp + (kb + 16 + lo) * HDc + 32 + 8 * hi);
        };
        loadK(k0, kc);

        for (int kb = k0; kb < kEnd; kb += 32) {
            // V fragments issued early (latency hides under QK + softmax)
            bf16x8 vf[4];
            #pragma unroll
            for (int d = 0; d < 4; ++d) {
                union { bf16x8 wv; bf16x4 h2[2]; } vv;
                const u16* vb = Vp + (16 * d + lo) * Tc + kb + 4 * hi;
                vv.h2[0] = *reinterpret_cast<const bf16x4*>(vb);
                vv.h2[1] = *reinterpret_cast<const bf16x4*>(vb + 16);
                vf[d] = vv.wv;
            }
            const bool more = (kb + 32 < kEnd);
            bf16x8 kn[4];
            if (more) loadK(kb + 32, kn);

            // S = K·Q^T (swapped): lane holds 8 keys for q = q0+lo
            f32x4 s[2][2];
            #pragma unroll
            for (int qt = 0; qt < 2; ++qt) {
                s[qt][0] = __builtin_amdgcn_mfma_f32_16x16x32_bf16(kc[0], qf[qt][0], fzero, 0, 0, 0);
                s[qt][0] = __builtin_amdgcn_mfma_f32_16x16x32_bf16(kc[1], qf[qt][1], s[qt][0], 0, 0, 0);
                s[qt][1] = __builtin_amdgcn_mfma_f32_16x16x32_bf16(kc[2], qf[qt][0], fzero, 0, 0, 0);
                s[qt][1] = __builtin_amdgcn_mfma_f32_16x16x32_bf16(kc[3], qf[qt][1], s[qt][1], 0, 0, 0);
            }

            // causal mask (only the diagonal tile)
            if (kb + 32 > qB) {
                #pragma unroll
                for (int qt = 0; qt < 2; ++qt)
                    #pragma unroll
                    for (int kt = 0; kt < 2; ++kt)
                        #pragma unroll
                        for (int r = 0; r < 4; ++r) {
                            const int key = kb + 16 * kt + 4 * hi + r;
                            const int q   = qB + 16 * qt + lo;
                            if (key > q) s[qt][kt][r] = -__builtin_inff();
                        }
            }

            float tm[2];
            #pragma unroll
            for (int qt = 0; qt < 2; ++qt) {
                float m01 = fmaxf(fmaxf(s[qt][0][0], s[qt][0][1]), fmaxf(s[qt][0][2], s[qt][0][3]));
                float m23 = fmaxf(fmaxf(s[qt][1][0], s[qt][1][1]), fmaxf(s[qt][1][2], s[qt][1][3]));
                float tmx = fmaxf(m01, m23);
                tmx = fmaxf(tmx, __shfl_xor(tmx, 16));
                tmx = fmaxf(tmx, __shfl_xor(tmx, 32));
                tm[qt] = tmx;
            }

            const bool deferOK = (tm[0] <= m2[0] + 11.5f) && (tm[1] <= m2[1] + 11.5f);
            if (!__all(deferOK)) {
                #pragma unroll
                for (int qt = 0; qt < 2; ++qt) {
                    const float mn = fmaxf(m2[qt], tm[qt]);
                    const float aq = exp2_hw(m2[qt] - mn);   // -inf -> 0 first tile
                    m2[qt] = mn;
                    l2[qt] *= aq;
                    float ar[4];
                    #pragma unroll
                    for (int r = 0; r < 4; ++r) ar[r] = __shfl(aq, 4 * hi + r);
                    #pragma unroll
                    for (int d = 0; d < 4; ++d)
                        #pragma unroll
                        for (int r = 0; r < 4; ++r) o[qt][d][r] *= ar[r];
                }
            }

            bf16x8 pa[2];
            #pragma unroll
            for (int qt = 0; qt < 2; ++qt) {
                float p[8];
                #pragma unroll
                for (int r = 0; r < 4; ++r) p[r]     = exp2_hw(s[qt][0][r] - m2[qt]);
                #pragma unroll
                for (int r = 0; r < 4; ++r) p[4 + r] = exp2_hw(s[qt][1][r] - m2[qt]);
                float ts = ((p[0] + p[1]) + (p[2] + p[3])) + ((p[4] + p[5]) + (p[6] + p[7]));
                ts += __shfl_xor(ts, 16);
                ts += __shfl_xor(ts, 32);
                l2[qt] += ts;
                union { bf16x8 v; unsigned wv[4]; } pk;
                pk.wv[0] = cvt_pk(p[0], p[1]);
                pk.wv[1] = cvt_pk(p[2], p[3]);
                pk.wv[2] = cvt_pk(p[4], p[5]);
                pk.wv[3] = cvt_pk(p[6], p[7]);
                pa[qt] = pk.v;
            }

            #pragma unroll
            for (int qt = 0; qt < 2; ++qt)
                #pragma unroll
                for (int d = 0; d < 4; ++d)
                    o[qt][d] = __builtin_amdgcn_mfma_f32_16x16x32_bf16(pa[qt], vf[d], o[qt][d], 0, 0, 0);

            if (more) {
                #pragma unroll
                for (int j = 0; j < 4; ++j) kc[j] = kn[j];
            }
        }
    }

    // ---- partial dump (waves 1..3) ----
    if (w != 0) {
        if (hi == 0) {
            #pragma unroll
            for (int qt = 0; qt < 2; ++qt) {
                mS[w - 1][16 * qt + lo] = m2[qt];
                lS[w - 1][16 * qt + lo] = l2[qt];
            }
        }
        #pragma unroll
        for (int qt = 0; qt < 2; ++qt)
            #pragma unroll
            for (int d = 0; d < 4; ++d)
                #pragma unroll
                for (int r = 0; r < 4; ++r)
                    oS[w - 1][16 * qt + 4 * hi + r][16 * d + lo] = o[qt][d][r];
    }
    __syncthreads();

    // ---- merge + write (wave 0) ----
    if (w == 0) {
        const int b = bh >> 4, h = bh & 15;
        #pragma unroll
        for (int qt = 0; qt < 2; ++qt) {
            float m0r[4], l0r[4], e0[4], Linv[4], es[3][4];
            #pragma unroll
            for (int r = 0; r < 4; ++r) {
                m0r[r] = __shfl(m2[qt], 4 * hi + r);
                l0r[r] = __shfl(l2[qt], 4 * hi + r);
            }
            #pragma unroll
            for (int r = 0; r < 4; ++r) {
                const int row = 16 * qt + 4 * hi + r;
                float M = m0r[r];
                #pragma unroll
                for (int s = 0; s < 3; ++s) M = fmaxf(M, mS[s][row]);
                e0[r] = exp2_hw(m0r[r] - M);
                float L = l0r[r] * e0[r];
                #pragma unroll
                for (int s = 0; s < 3; ++s) {
                    const float e = exp2_hw(mS[s][row] - M);
                    es[s][r] = e;
                    L += lS[s][row] * e;
                }
                Linv[r] = 1.0f / L;
            }
            #pragma unroll
            for (int d = 0; d < 4; ++d)
                #pragma unroll
                for (int r = 0; r < 4; ++r) {
                    const int row = 16 * qt + 4 * hi + r;
                    float acc = o[qt][d][r] * e0[r];
                    #pragma unroll
                    for (int s = 0; s < 3; ++s)
                        acc += oS[s][row][16 * d + lo] * es[s][r];
                    const int q = qB + row;
                    O[(size_t)(b * Tc + q) * Dc + h * 64 + 16 * d + lo] = f2b(acc * Linv[r]);
                }
        }
    }
}

// ---------------- host launcher ----------------
extern "C" void kernel_launch(void* const* d_in, const int* in_sizes, int n_in,
                              void* d_out, int out_size, void* d_ws, size_t ws_size,
                              hipStream_t stream) {
    (void)in_sizes; (void)n_in; (void)out_size; (void)ws_size;
    const float* x  = (const float*)d_in[0];
    const float* Wk = (const float*)d_in[1];
    const float* Wq = (const float*)d_in[2];
    const float* Wv = (const float*)d_in[3];
    const float* Wp = (const float*)d_in[4];
    const float* bp = (const float*)d_in[5];
    float* out = (float*)d_out;

    char* ws = (char*)d_ws;
    u16* xb   = (u16*)(ws);
    u16* wqb  = (u16*)(ws + (8u  << 20));
    u16* wkb  = (u16*)(ws + (10u << 20));
    u16* wvb  = (u16*)(ws + (12u << 20));
    u16* wpb  = (u16*)(ws + (14u << 20));
    u16* Qb   = (u16*)(ws + (16u << 20));
    u16* Kb   = (u16*)(ws + (24u << 20));
    u16* Vtb  = (u16*)(ws + (32u << 20));
    u16* attb = (u16*)(ws + (40u << 20));

    CvtArgs ca;
    ca.src[0] = x;  ca.dst[0] = xb;  ca.n[0] = Mg * Dc;
    ca.src[1] = Wq; ca.dst[1] = wqb; ca.n[1] = Dc * Dc;
    ca.src[2] = Wk; ca.dst[2] = wkb; ca.n[2] = Dc * Dc;
    ca.src[3] = Wv; ca.dst[3] = wvb; ca.n[3] = Dc * Dc;
    ca.src[4] = Wp; ca.dst[4] = wpb; ca.n[4] = Dc * Dc;
    cvt_all<<<dim3(1024), 256, 0, stream>>>(ca);

    gemm_bt<0><<<dim3(Dc / 128, Mg / 128, 3), 256, 0, stream>>>(
        xb, wqb, wkb, wvb, Qb, Kb, Vtb, nullptr, nullptr);

    attn_kernel<<<dim3(Tc / 32, Bc * Hc), 256, 0, stream>>>(Qb, Kb, Vtb, attb);

    gemm_bt<1><<<dim3(Dc / 128, Mg / 128, 1), 256, 0, stream>>>(
        attb, wpb, wpb, wpb, nullptr, nullptr, nullptr, bp, out);
}

// Round 5
// 147.495 us; speedup vs baseline: 2.1797x; 1.6057x over previous
//
#include <hip/hip_runtime.h>

typedef unsigned short u16;
typedef __bf16 bf16;
typedef bf16  bf16x8 __attribute__((ext_vector_type(8)));
typedef float f32x4  __attribute__((ext_vector_type(4)));

constexpr int Bc  = 2;
constexpr int Tc  = 2048;
constexpr int Dc  = 1024;
constexpr int Hc  = 16;
constexpr int HDc = 64;
constexpr int Mg  = Bc * Tc;   // 4096 tokens
constexpr int Kg  = Dc;        // 1024 reduction dim

// round-to-nearest-even f32 -> bf16 (finite inputs only)
__device__ inline u16 f2b(float f) {
    union { float f; unsigned u; } c; c.f = f;
    unsigned r = c.u + 0x7FFFu + ((c.u >> 16) & 1u);
    return (u16)(r >> 16);
}

__device__ inline float exp2_hw(float x) {
    float r; asm("v_exp_f32 %0, %1" : "=v"(r) : "v"(x)); return r;
}
__device__ inline unsigned cvt_pk(float a, float b) {
    unsigned r; asm("v_cvt_pk_bf16_f32 %0, %1, %2" : "=v"(r) : "v"(a), "v"(b)); return r;
}
__device__ inline void gload16(const u16* g, u16* l) {
    __builtin_amdgcn_global_load_lds(
        (const __attribute__((address_space(1))) void*)g,
        (__attribute__((address_space(3))) void*)l, 16, 0, 0);
}

// ---------------- fused fp32 -> bf16 conversion (all 5 tensors, 1 launch) --------
struct CvtArgs { const float* src[5]; u16* dst[5]; int n[5]; };

__global__ __launch_bounds__(256) void cvt_all(CvtArgs a) {
    const int tid = blockIdx.x * blockDim.x + threadIdx.x;
    const int stride = gridDim.x * blockDim.x * 4;
    #pragma unroll
    for (int r = 0; r < 5; ++r) {
        const float* s = a.src[r];
        u16* d = a.dst[r];
        const int n = a.n[r];
        for (int i = tid * 4; i < n; i += stride) {
            float4 v = *reinterpret_cast<const float4*>(s + i);
            ushort4 o;
            o.x = f2b(v.x); o.y = f2b(v.y); o.z = f2b(v.z); o.w = f2b(v.w);
            *reinterpret_cast<ushort4*>(d + i) = o;
        }
    }
}

// ---------------- GEMM: C[M,N] = A[M,K] * W[N,K]^T (m97 structure) ----------------
// EPI==0: z selects {Q,K,V}; Q/K -> [B,H,T,HD]; V -> permuted panel layout
//   Vp[bh][tile=t/64][row=hd][slot 0..7][8 elems]:
//   slot 4*p2+s holds keys 64*tile + 32*p2 + {4s..4s+3, 16+4s..16+4s+3}.
template<int EPI>
__global__ __launch_bounds__(256) void gemm_bt(
    const u16* __restrict__ A,
    const u16* __restrict__ W0, const u16* __restrict__ W1, const u16* __restrict__ W2,
    u16* __restrict__ dQ, u16* __restrict__ dK, u16* __restrict__ dV,
    const float* __restrict__ bias, float* __restrict__ outF)
{
    __shared__ u16 As[128 * 32];
    __shared__ u16 Bs[128 * 32];

    const int t    = threadIdx.x;
    const int z    = blockIdx.z;
    const int m0   = blockIdx.y * 128;
    const int n0   = blockIdx.x * 128;
    const u16* Wsel = (z == 0) ? W0 : (z == 1) ? W1 : W2;

    const int lane = t & 63, wave = t >> 6;
    const int wm = wave >> 1, wn = wave & 1;
    const int lo = lane & 15, hi = lane >> 4;

    f32x4 acc[4][4];
    const f32x4 fzero = {0.f, 0.f, 0.f, 0.f};
    #pragma unroll
    for (int i = 0; i < 4; ++i)
        #pragma unroll
        for (int j = 0; j < 4; ++j) acc[i][j] = fzero;

    const int rA = t >> 2;
    const int ks = ((t & 3) ^ (rA & 3)) * 8;
    const u16* gA0 = A    + (size_t)(m0 + rA) * Kg + ks;
    const u16* gA1 = gA0 + 64 * Kg;
    const u16* gB0 = Wsel + (size_t)(n0 + rA) * Kg + ks;
    const u16* gB1 = gB0 + 64 * Kg;
    u16* lA0 = &As[(wave * 16) * 32];
    u16* lA1 = &As[(64 + wave * 16) * 32];
    u16* lB0 = &Bs[(wave * 16) * 32];
    u16* lB1 = &Bs[(64 + wave * 16) * 32];

    const int sl = (hi ^ (lo & 3)) * 8;

    for (int k0 = 0; k0 < Kg; k0 += 32) {
        __syncthreads();
        gload16(gA0 + k0, lA0);
        gload16(gA1 + k0, lA1);
        gload16(gB0 + k0, lB0);
        gload16(gB1 + k0, lB1);
        __syncthreads();

        bf16x8 af[4], bfr[4];
        #pragma unroll
        for (int fi = 0; fi < 4; ++fi)
            af[fi] = *reinterpret_cast<const bf16x8*>(&As[(wm * 64 + fi * 16 + lo) * 32 + sl]);
        #pragma unroll
        for (int fj = 0; fj < 4; ++fj)
            bfr[fj] = *reinterpret_cast<const bf16x8*>(&Bs[(wn * 64 + fj * 16 + lo) * 32 + sl]);
        #pragma unroll
        for (int fi = 0; fi < 4; ++fi)
            #pragma unroll
            for (int fj = 0; fj < 4; ++fj)
                acc[fi][fj] = __builtin_amdgcn_mfma_f32_16x16x32_bf16(af[fi], bfr[fj], acc[fi][fj], 0, 0, 0);
    }

    #pragma unroll
    for (int fi = 0; fi < 4; ++fi) {
        #pragma unroll
        for (int fj = 0; fj < 4; ++fj) {
            const int nn = n0 + wn * 64 + fj * 16 + lo;
            if constexpr (EPI == 0) {
                const int b = m0 >> 11;
                const int h = nn >> 6, hd = nn & 63;
                if (z == 2) {
                    const int tt0 = (m0 & (Tc - 1)) + wm * 64 + fi * 16 + hi * 4;
                    const int tile = tt0 >> 6;
                    const int k6   = tt0 & 63;
                    const int slot = ((k6 & 32) >> 3) + ((k6 & 15) >> 2);
                    const int halfE = (k6 & 16) >> 2;            // 0 or 4 elems
                    const size_t off =
                        (((size_t)(b * Hc + h) * 32 + tile) * 64 + hd) * 64 + slot * 8 + halfE;
                    ushort4 pv;
                    pv.x = f2b(acc[fi][fj][0]); pv.y = f2b(acc[fi][fj][1]);
                    pv.z = f2b(acc[fi][fj][2]); pv.w = f2b(acc[fi][fj][3]);
                    *reinterpret_cast<ushort4*>(&dV[off]) = pv;
                } else {
                    u16* dst = (z == 0) ? dQ : dK;
                    #pragma unroll
                    for (int r = 0; r < 4; ++r) {
                        const int m = m0 + wm * 64 + fi * 16 + hi * 4 + r;
                        const int tt = m & (Tc - 1);
                        dst[((((b * Hc + h) << 11) + tt) * HDc) + hd] = f2b(acc[fi][fj][r]);
                    }
                }
            } else {
                #pragma unroll
                for (int r = 0; r < 4; ++r) {
                    const int m = m0 + wm * 64 + fi * 16 + hi * 4 + r;
                    outF[(size_t)m * Dc + nn] = acc[fi][fj][r] + bias[nn];
                }
            }
        }
    }
}

// ---------------- causal flash attention: LDS-shared K/V, paired q-tiles ----------
// Block (bi, bh) = 4 waves; wave w owns pair p = bi + 8w: low tile rows [32p,+32),
// high tile rows [32(63-p),+32). All waves consume one shared K/V stream staged in
// double-buffered, XOR-swizzled LDS via global_load_lds (width 16). Per-wave compute
// = exactly 65 32-key substeps (balanced); no merge needed.
__global__ __launch_bounds__(256) void attn_kernel(const u16* __restrict__ Q,
                                                   const u16* __restrict__ Kk,
                                                   const u16* __restrict__ Vp,
                                                   u16* __restrict__ O)
{
    __shared__ u16 Kl[2][64][64];
    __shared__ u16 Vl[2][64][64];

    const int t = threadIdx.x;
    const int w = t >> 6;
    const int lane = t & 63;
    const int lo = lane & 15, hi = lane >> 4;
    const int l8 = lane >> 3, l7 = lane & 7;
    const int bi = blockIdx.x;                     // 0..7
    const int bh = blockIdx.y;
    const int p  = bi + 8 * w;                     // pair 0..31
    const int ql0 = 32 * p;
    const int qh0 = 32 * (63 - p);
    const int NT = (Tc - 32 * bi + 63) >> 6;       // block tile count (64-key tiles)

    const u16* Qp = Q  + (size_t)bh * Tc * HDc;
    const u16* Kp = Kk + (size_t)bh * Tc * HDc;
    const u16* Vq = Vp + (size_t)bh * Tc * HDc;    // permuted panel image

    const float sc2 = 0.125f * 1.44269504f;
    const f32x4 fzero = {0.f, 0.f, 0.f, 0.f};

    // Q fragments for both tiles, prescaled into exp2 domain
    bf16x8 qfl[2][2], qfh[2][2];
    #pragma unroll
    for (int qt = 0; qt < 2; ++qt)
        #pragma unroll
        for (int h = 0; h < 2; ++h) {
            union { bf16x8 v; u16 u[8]; } a2, r2;
            a2.v = *reinterpret_cast<const bf16x8*>(Qp + (ql0 + 16 * qt + lo) * HDc + 32 * h + 8 * hi);
            #pragma unroll
            for (int j = 0; j < 8; ++j) {
                union { float f; unsigned u; } c; c.u = ((unsigned)a2.u[j]) << 16;
                r2.u[j] = f2b(c.f * sc2);
            }
            qfl[qt][h] = r2.v;
            a2.v = *reinterpret_cast<const bf16x8*>(Qp + (qh0 + 16 * qt + lo) * HDc + 32 * h + 8 * hi);
            #pragma unroll
            for (int j = 0; j < 8; ++j) {
                union { float f; unsigned u; } c; c.u = ((unsigned)a2.u[j]) << 16;
                r2.u[j] = f2b(c.f * sc2);
            }
            qfh[qt][h] = r2.v;
        }

    f32x4 ol[2][4], oh[2][4];
    float ml2[2] = {-__builtin_inff(), -__builtin_inff()};
    float mh2[2] = {-__builtin_inff(), -__builtin_inff()};
    float ll2[2] = {0.f, 0.f};
    float lh2[2] = {0.f, 0.f};
    #pragma unroll
    for (int qt = 0; qt < 2; ++qt)
        #pragma unroll
        for (int d = 0; d < 4; ++d) { ol[qt][d] = fzero; oh[qt][d] = fzero; }

    // staging: wave w covers rows 16w..16w+15 of each 8KB tile (K and V)
    const int rb = 16 * w;
    const int swz = (l7 ^ l8) * 8;                 // pre-swizzled source slot
    auto stage = [&](int tile, int b) {
        const u16* ksrc = Kp + (size_t)(tile * 64 + rb + l8) * 64 + swz;
        const u16* vsrc = Vq + (size_t)(tile * 64 + rb + l8) * 64 + swz;
        gload16(ksrc,           &Kl[b][rb][0]);
        gload16(ksrc + 8 * 64,  &Kl[b][rb + 8][0]);
        gload16(vsrc,           &Vl[b][rb][0]);
        gload16(vsrc + 8 * 64,  &Vl[b][rb + 8][0]);
    };

    // one 32-key substep for one q-tile
    auto sub = [&](int kb, int q0v, const bf16x8 (&qv)[2], f32x4 (&ov)[2][4],
                   float (&m2)[2], float (&l2)[2],
                   const bf16x8& kf00, const bf16x8& kf01,
                   const bf16x8& kf10, const bf16x8& kf11, const bf16x8 (&vf)[4]) {
        f32x4 s[2][2];
        #pragma unroll
        for (int qt = 0; qt < 2; ++qt) {
            s[qt][0] = __builtin_amdgcn_mfma_f32_16x16x32_bf16(kf00, qv[qt * 2 + 0 - qt], s[qt][0], 0, 0, 0); // placeholder
        }
        (void)s;
    };
    (void)sub;

    stage(0, 0);
    __syncthreads();

    for (int tt = 0; tt < NT; ++tt) {
        const int cur = tt & 1;
        if (tt + 1 < NT) stage(tt + 1, cur ^ 1);
        const int kb64 = tt << 6;

        #pragma unroll
        for (int p2 = 0; p2 < 2; ++p2) {
            const int kb = kb64 + 32 * p2;
            if (kb > qh0 + 31) break;              // wave done (keeps staging/barriers)

            // K fragments from LDS (swizzled)
            const int sw = lo & 7;
            const bf16x8 kf00 = *reinterpret_cast<const bf16x8*>(&Kl[cur][32 * p2 + lo     ][(hi ^ sw) * 8]);
            const bf16x8 kf01 = *reinterpret_cast<const bf16x8*>(&Kl[cur][32 * p2 + lo     ][((4 + hi) ^ sw) * 8]);
            const bf16x8 kf10 = *reinterpret_cast<const bf16x8*>(&Kl[cur][32 * p2 + 16 + lo][(hi ^ sw) * 8]);
            const bf16x8 kf11 = *reinterpret_cast<const bf16x8*>(&Kl[cur][32 * p2 + 16 + lo][((4 + hi) ^ sw) * 8]);
            bf16x8 vf[4];
            #pragma unroll
            for (int d = 0; d < 4; ++d)
                vf[d] = *reinterpret_cast<const bf16x8*>(&Vl[cur][16 * d + lo][((4 * p2 + hi) ^ sw) * 8]);

            // ---- high tile (always active while kb <= qh0+31) ----
            {
                f32x4 s0, s1;
                s0 = __builtin_amdgcn_mfma_f32_16x16x32_bf16(kf00, qfh[0][0], fzero, 0, 0, 0);
                s0 = __builtin_amdgcn_mfma_f32_16x16x32_bf16(kf01, qfh[0][1], s0, 0, 0, 0);
                s1 = __builtin_amdgcn_mfma_f32_16x16x32_bf16(kf10, qfh[0][0], fzero, 0, 0, 0);
                s1 = __builtin_amdgcn_mfma_f32_16x16x32_bf16(kf11, qfh[0][1], s1, 0, 0, 0);
                f32x4 s2, s3;
                s2 = __builtin_amdgcn_mfma_f32_16x16x32_bf16(kf00, qfh[1][0], fzero, 0, 0, 0);
                s2 = __builtin_amdgcn_mfma_f32_16x16x32_bf16(kf01, qfh[1][1], s2, 0, 0, 0);
                s3 = __builtin_amdgcn_mfma_f32_16x16x32_bf16(kf10, qfh[1][0], fzero, 0, 0, 0);
                s3 = __builtin_amdgcn_mfma_f32_16x16x32_bf16(kf11, qfh[1][1], s3, 0, 0, 0);
                f32x4 s[2][2] = {{s0, s1}, {s2, s3}};

                if (kb == qh0) {
                    #pragma unroll
                    for (int qt = 0; qt < 2; ++qt)
                        #pragma unroll
                        for (int kt = 0; kt < 2; ++kt)
                            #pragma unroll
                            for (int r = 0; r < 4; ++r)
                                if (kb + 16 * kt + 4 * hi + r > qh0 + 16 * qt + lo)
                                    s[qt][kt][r] = -__builtin_inff();
                }
                float tm[2];
                #pragma unroll
                for (int qt = 0; qt < 2; ++qt) {
                    float a = fmaxf(fmaxf(s[qt][0][0], s[qt][0][1]), fmaxf(s[qt][0][2], s[qt][0][3]));
                    float b2 = fmaxf(fmaxf(s[qt][1][0], s[qt][1][1]), fmaxf(s[qt][1][2], s[qt][1][3]));
                    float x = fmaxf(a, b2);
                    x = fmaxf(x, __shfl_xor(x, 16));
                    x = fmaxf(x, __shfl_xor(x, 32));
                    tm[qt] = x;
                }
                if (!__all((tm[0] <= mh2[0] + 11.5f) && (tm[1] <= mh2[1] + 11.5f))) {
                    #pragma unroll
                    for (int qt = 0; qt < 2; ++qt) {
                        const float mn = fmaxf(mh2[qt], tm[qt]);
                        const float aq = exp2_hw(mh2[qt] - mn);
                        mh2[qt] = mn;
                        lh2[qt] *= aq;
                        float ar[4];
                        #pragma unroll
                        for (int r = 0; r < 4; ++r) ar[r] = __shfl(aq, 4 * hi + r);
                        #pragma unroll
                        for (int d = 0; d < 4; ++d)
                            #pragma unroll
                            for (int r = 0; r < 4; ++r) oh[qt][d][r] *= ar[r];
                    }
                }
                #pragma unroll
                for (int qt = 0; qt < 2; ++qt) {
                    float pr[8];
                    #pragma unroll
                    for (int r = 0; r < 4; ++r) pr[r]     = exp2_hw(s[qt][0][r] - mh2[qt]);
                    #pragma unroll
                    for (int r = 0; r < 4; ++r) pr[4 + r] = exp2_hw(s[qt][1][r] - mh2[qt]);
                    float ts = ((pr[0] + pr[1]) + (pr[2] + pr[3])) + ((pr[4] + pr[5]) + (pr[6] + pr[7]));
                    ts += __shfl_xor(ts, 16);
                    ts += __shfl_xor(ts, 32);
                    lh2[qt] += ts;
                    union { bf16x8 v; unsigned wv[4]; } pk;
                    pk.wv[0] = cvt_pk(pr[0], pr[1]);
                    pk.wv[1] = cvt_pk(pr[2], pr[3]);
                    pk.wv[2] = cvt_pk(pr[4], pr[5]);
                    pk.wv[3] = cvt_pk(pr[6], pr[7]);
                    #pragma unroll
                    for (int d = 0; d < 4; ++d)
                        oh[qt][d] = __builtin_amdgcn_mfma_f32_16x16x32_bf16(pk.v, vf[d], oh[qt][d], 0, 0, 0);
                }
            }

            // ---- low tile (active only for early kb) ----
            if (kb <= ql0 + 31) {
                f32x4 s0, s1;
                s0 = __builtin_amdgcn_mfma_f32_16x16x32_bf16(kf00, qfl[0][0], fzero, 0, 0, 0);
                s0 = __builtin_amdgcn_mfma_f32_16x16x32_bf16(kf01, qfl[0][1], s0, 0, 0, 0);
                s1 = __builtin_amdgcn_mfma_f32_16x16x32_bf16(kf10, qfl[0][0], fzero, 0, 0, 0);
                s1 = __builtin_amdgcn_mfma_f32_16x16x32_bf16(kf11, qfl[0][1], s1, 0, 0, 0);
                f32x4 s2, s3;
                s2 = __builtin_amdgcn_mfma_f32_16x16x32_bf16(kf00, qfl[1][0], fzero, 0, 0, 0);
                s2 = __builtin_amdgcn_mfma_f32_16x16x32_bf16(kf01, qfl[1][1], s2, 0, 0, 0);
                s3 = __builtin_amdgcn_mfma_f32_16x16x32_bf16(kf10, qfl[1][0], fzero, 0, 0, 0);
                s3 = __builtin_amdgcn_mfma_f32_16x16x32_bf16(kf11, qfl[1][1], s3, 0, 0, 0);
                f32x4 s[2][2] = {{s0, s1}, {s2, s3}};

                if (kb == ql0) {
                    #pragma unroll
                    for (int qt = 0; qt < 2; ++qt)
                        #pragma unroll
                        for (int kt = 0; kt < 2; ++kt)
                            #pragma unroll
                            for (int r = 0; r < 4; ++r)
                                if (kb + 16 * kt + 4 * hi + r > ql0 + 16 * qt + lo)
                                    s[qt][kt][r] = -__builtin_inff();
                }
                float tm[2];
                #pragma unroll
                for (int qt = 0; qt < 2; ++qt) {
                    float a = fmaxf(fmaxf(s[qt][0][0], s[qt][0][1]), fmaxf(s[qt][0][2], s[qt][0][3]));
                    float b2 = fmaxf(fmaxf(s[qt][1][0], s[qt][1][1]), fmaxf(s[qt][1][2], s[qt][1][3]));
                    float x = fmaxf(a, b2);
                    x = fmaxf(x, __shfl_xor(x, 16));
                    x = fmaxf(x, __shfl_xor(x, 32));
                    tm[qt] = x;
                }
                if (!__all((tm[0] <= ml2[0] + 11.5f) && (tm[1] <= ml2[1] + 11.5f))) {
                    #pragma unroll
                    for (int qt = 0; qt < 2; ++qt) {
                        const float mn = fmaxf(ml2[qt], tm[qt]);
                        const float aq = exp2_hw(ml2[qt] - mn);
                        ml2[qt] = mn;
                        ll2[qt] *= aq;
                        float ar[4];
                        #pragma unroll
                        for (int r = 0; r < 4; ++r) ar[r] = __shfl(aq, 4 * hi + r);
                        #pragma unroll
                        for (int d = 0; d < 4; ++d)
                            #pragma unroll
                            for (int r = 0; r < 4; ++r) ol[qt][d][r] *= ar[r];
                    }
                }
                #pragma unroll
                for (int qt = 0; qt < 2; ++qt) {
                    float pr[8];
                    #pragma unroll
                    for (int r = 0; r < 4; ++r) pr[r]     = exp2_hw(s[qt][0][r] - ml2[qt]);
                    #pragma unroll
                    for (int r = 0; r < 4; ++r) pr[4 + r] = exp2_hw(s[qt][1][r] - ml2[qt]);
                    float ts = ((pr[0] + pr[1]) + (pr[2] + pr[3])) + ((pr[4] + pr[5]) + (pr[6] + pr[7]));
                    ts += __shfl_xor(ts, 16);
                    ts += __shfl_xor(ts, 32);
                    ll2[qt] += ts;
                    union { bf16x8 v; unsigned wv[4]; } pk;
                    pk.wv[0] = cvt_pk(pr[0], pr[1]);
                    pk.wv[1] = cvt_pk(pr[2], pr[3]);
                    pk.wv[2] = cvt_pk(pr[4], pr[5]);
                    pk.wv[3] = cvt_pk(pr[6], pr[7]);
                    #pragma unroll
                    for (int d = 0; d < 4; ++d)
                        ol[qt][d] = __builtin_amdgcn_mfma_f32_16x16x32_bf16(pk.v, vf[d], ol[qt][d], 0, 0, 0);
                }
            }
        }
        __syncthreads();
    }

    // ---- epilogue: normalize + write both tiles ----
    const int b = bh >> 4, h = bh & 15;
    #pragma unroll
    for (int qt = 0; qt < 2; ++qt) {
        float li[4];
        #pragma unroll
        for (int r = 0; r < 4; ++r) li[r] = 1.0f / __shfl(ll2[qt], 4 * hi + r);
        #pragma unroll
        for (int d = 0; d < 4; ++d)
            #pragma unroll
            for (int r = 0; r < 4; ++r) {
                const int q = ql0 + 16 * qt + 4 * hi + r;
                O[(size_t)(b * Tc + q) * Dc + h * 64 + 16 * d + lo] = f2b(ol[qt][d][r] * li[r]);
            }
        #pragma unroll
        for (int r = 0; r < 4; ++r) li[r] = 1.0f / __shfl(lh2[qt], 4 * hi + r);
        #pragma unroll
        for (int d = 0; d < 4; ++d)
            #pragma unroll
            for (int r = 0; r < 4; ++r) {
                const int q = qh0 + 16 * qt + 4 * hi + r;
                O[(size_t)(b * Tc + q) * Dc + h * 64 + 16 * d + lo] = f2b(oh[qt][d][r] * li[r]);
            }
    }
}

// ---------------- host launcher ----------------
extern "C" void kernel_launch(void* const* d_in, const int* in_sizes, int n_in,
                              void* d_out, int out_size, void* d_ws, size_t ws_size,
                              hipStream_t stream) {
    (void)in_sizes; (void)n_in; (void)out_size; (void)ws_size;
    const float* x  = (const float*)d_in[0];
    const float* Wk = (const float*)d_in[1];
    const float* Wq = (const float*)d_in[2];
    const float* Wv = (const float*)d_in[3];
    const float* Wp = (const float*)d_in[4];
    const float* bp = (const float*)d_in[5];
    float* out = (float*)d_out;

    char* ws = (char*)d_ws;
    u16* xb   = (u16*)(ws);
    u16* wqb  = (u16*)(ws + (8u  << 20));
    u16* wkb  = (u16*)(ws + (10u << 20));
    u16* wvb  = (u16*)(ws + (12u << 20));
    u16* wpb  = (u16*)(ws + (14u << 20));
    u16* Qb   = (u16*)(ws + (16u << 20));
    u16* Kb   = (u16*)(ws + (24u << 20));
    u16* Vtb  = (u16*)(ws + (32u << 20));   // permuted V panels
    u16* attb = (u16*)(ws + (40u << 20));

    CvtArgs ca;
    ca.src[0] = x;  ca.dst[0] = xb;  ca.n[0] = Mg * Dc;
    ca.src[1] = Wq; ca.dst[1] = wqb; ca.n[1] = Dc * Dc;
    ca.src[2] = Wk; ca.dst[2] = wkb; ca.n[2] = Dc * Dc;
    ca.src[3] = Wv; ca.dst[3] = wvb; ca.n[3] = Dc * Dc;
    ca.src[4] = Wp; ca.dst[4] = wpb; ca.n[4] = Dc * Dc;
    cvt_all<<<dim3(1024), 256, 0, stream>>>(ca);

    gemm_bt<0><<<dim3(Dc / 128, Mg / 128, 3), 256, 0, stream>>>(
        xb, wqb, wkb, wvb, Qb, Kb, Vtb, nullptr, nullptr);

    attn_kernel<<<dim3(8, Bc * Hc), 256, 0, stream>>>(Qb, Kb, Vtb, attb);

    gemm_bt<1><<<dim3(Dc / 128, Mg / 128, 1), 256, 0, stream>>>(
        attb, wpb, wpb, wpb, nullptr, nullptr, nullptr, bp, out);
}

// Round 7
// 125.744 us; speedup vs baseline: 2.5567x; 1.1730x over previous
//
#include <hip/hip_runtime.h>

typedef unsigned short u16;
typedef __bf16 bf16;
typedef bf16  bf16x8 __attribute__((ext_vector_type(8)));
typedef float f32x4  __attribute__((ext_vector_type(4)));

constexpr int Bc  = 2;
constexpr int Tc  = 2048;
constexpr int Dc  = 1024;
constexpr int Hc  = 16;
constexpr int HDc = 64;
constexpr int Mg  = Bc * Tc;   // 4096 tokens
constexpr int Kg  = Dc;        // 1024 reduction dim

// round-to-nearest-even f32 -> bf16 (finite inputs only)
__device__ inline u16 f2b(float f) {
    union { float f; unsigned u; } c; c.f = f;
    unsigned r = c.u + 0x7FFFu + ((c.u >> 16) & 1u);
    return (u16)(r >> 16);
}

__device__ inline float exp2_hw(float x) {
    float r; asm("v_exp_f32 %0, %1" : "=v"(r) : "v"(x)); return r;
}
__device__ inline unsigned cvt_pk(float a, float b) {
    unsigned r; asm("v_cvt_pk_bf16_f32 %0, %1, %2" : "=v"(r) : "v"(a), "v"(b)); return r;
}
__device__ inline void gload16(const u16* g, u16* l) {
    __builtin_amdgcn_global_load_lds(
        (const __attribute__((address_space(1))) void*)g,
        (__attribute__((address_space(3))) void*)l, 16, 0, 0);
}

// ---------------- fused fp32 -> bf16 conversion (all 5 tensors, 1 launch) --------
struct CvtArgs { const float* src[5]; u16* dst[5]; int n[5]; };

__global__ __launch_bounds__(256) void cvt_all(CvtArgs a) {
    const int tid = blockIdx.x * blockDim.x + threadIdx.x;
    const int stride = gridDim.x * blockDim.x * 4;
    #pragma unroll
    for (int r = 0; r < 5; ++r) {
        const float* s = a.src[r];
        u16* d = a.dst[r];
        const int n = a.n[r];
        for (int i = tid * 4; i < n; i += stride) {
            float4 v = *reinterpret_cast<const float4*>(s + i);
            ushort4 o;
            o.x = f2b(v.x); o.y = f2b(v.y); o.z = f2b(v.z); o.w = f2b(v.w);
            *reinterpret_cast<ushort4*>(d + i) = o;
        }
    }
}

// ---------------- GEMM: C[M,N] = A[M,K] * W[N,K]^T (m97 structure) ----------------
// EPI==0: z selects {Q,K,V}; Q/K -> [B,H,T,HD]; V -> permuted panel layout
//   Vp[bh][tile=t/64][row=hd][slot 0..7][8 elems]:
//   slot 4*c+s holds keys 64*tile + 32*c + {4s..4s+3, 16+4s..16+4s+3}.
template<int EPI>
__global__ __launch_bounds__(256) void gemm_bt(
    const u16* __restrict__ A,
    const u16* __restrict__ W0, const u16* __restrict__ W1, const u16* __restrict__ W2,
    u16* __restrict__ dQ, u16* __restrict__ dK, u16* __restrict__ dV,
    const float* __restrict__ bias, float* __restrict__ outF)
{
    __shared__ u16 As[128 * 32];
    __shared__ u16 Bs[128 * 32];

    const int t    = threadIdx.x;
    const int z    = blockIdx.z;
    const int m0   = blockIdx.y * 128;
    const int n0   = blockIdx.x * 128;
    const u16* Wsel = (z == 0) ? W0 : (z == 1) ? W1 : W2;

    const int lane = t & 63, wave = t >> 6;
    const int wm = wave >> 1, wn = wave & 1;
    const int lo = lane & 15, hi = lane >> 4;

    f32x4 acc[4][4];
    const f32x4 fzero = {0.f, 0.f, 0.f, 0.f};
    #pragma unroll
    for (int i = 0; i < 4; ++i)
        #pragma unroll
        for (int j = 0; j < 4; ++j) acc[i][j] = fzero;

    const int rA = t >> 2;
    const int ks = ((t & 3) ^ (rA & 3)) * 8;
    const u16* gA0 = A    + (size_t)(m0 + rA) * Kg + ks;
    const u16* gA1 = gA0 + 64 * Kg;
    const u16* gB0 = Wsel + (size_t)(n0 + rA) * Kg + ks;
    const u16* gB1 = gB0 + 64 * Kg;
    u16* lA0 = &As[(wave * 16) * 32];
    u16* lA1 = &As[(64 + wave * 16) * 32];
    u16* lB0 = &Bs[(wave * 16) * 32];
    u16* lB1 = &Bs[(64 + wave * 16) * 32];

    const int sl = (hi ^ (lo & 3)) * 8;

    for (int k0 = 0; k0 < Kg; k0 += 32) {
        __syncthreads();
        gload16(gA0 + k0, lA0);
        gload16(gA1 + k0, lA1);
        gload16(gB0 + k0, lB0);
        gload16(gB1 + k0, lB1);
        __syncthreads();

        bf16x8 af[4], bfr[4];
        #pragma unroll
        for (int fi = 0; fi < 4; ++fi)
            af[fi] = *reinterpret_cast<const bf16x8*>(&As[(wm * 64 + fi * 16 + lo) * 32 + sl]);
        #pragma unroll
        for (int fj = 0; fj < 4; ++fj)
            bfr[fj] = *reinterpret_cast<const bf16x8*>(&Bs[(wn * 64 + fj * 16 + lo) * 32 + sl]);
        #pragma unroll
        for (int fi = 0; fi < 4; ++fi)
            #pragma unroll
            for (int fj = 0; fj < 4; ++fj)
                acc[fi][fj] = __builtin_amdgcn_mfma_f32_16x16x32_bf16(af[fi], bfr[fj], acc[fi][fj], 0, 0, 0);
    }

    #pragma unroll
    for (int fi = 0; fi < 4; ++fi) {
        #pragma unroll
        for (int fj = 0; fj < 4; ++fj) {
            const int nn = n0 + wn * 64 + fj * 16 + lo;
            if constexpr (EPI == 0) {
                const int b = m0 >> 11;
                const int h = nn >> 6, hd = nn & 63;
                if (z == 2) {
                    const int tt0 = (m0 & (Tc - 1)) + wm * 64 + fi * 16 + hi * 4;
                    const int tile = tt0 >> 6;
                    const int k6   = tt0 & 63;
                    const int slot = ((k6 & 32) >> 3) + ((k6 & 15) >> 2);
                    const int halfE = (k6 & 16) >> 2;            // 0 or 4 elems
                    const size_t off =
                        (((size_t)(b * Hc + h) * 32 + tile) * 64 + hd) * 64 + slot * 8 + halfE;
                    ushort4 pv;
                    pv.x = f2b(acc[fi][fj][0]); pv.y = f2b(acc[fi][fj][1]);
                    pv.z = f2b(acc[fi][fj][2]); pv.w = f2b(acc[fi][fj][3]);
                    *reinterpret_cast<ushort4*>(&dV[off]) = pv;
                } else {
                    u16* dst = (z == 0) ? dQ : dK;
                    #pragma unroll
                    for (int r = 0; r < 4; ++r) {
                        const int m = m0 + wm * 64 + fi * 16 + hi * 4 + r;
                        const int tt = m & (Tc - 1);
                        dst[((((b * Hc + h) << 11) + tt) * HDc) + hd] = f2b(acc[fi][fj][r]);
                    }
                }
            } else {
                #pragma unroll
                for (int r = 0; r < 4; ++r) {
                    const int m = m0 + wm * 64 + fi * 16 + hi * 4 + r;
                    outF[(size_t)m * Dc + nn] = acc[fi][fj][r] + bias[nn];
                }
            }
        }
    }
}

// ---------------- causal flash attention: LDS-shared K/V, 16-row paired tiles -----
// Block (bi,bh), bi in 0..15, 4 waves. Wave w owns pair p = bi + 16w of 16-row
// tiles: low rows [16p,+16), high rows [16(127-p),+16). Every wave: ~64.5 32-key
// substeps (balanced). K/V staged via global_load_lds into XOR-swizzled
// double-buffered LDS. Shfl-free steady-state online softmax (lane-local gate,
// lane-local l; row reductions only on rescale + once in epilogue). No merges:
// each wave owns complete rows.
__global__ __launch_bounds__(256) void attn_kernel(const u16* __restrict__ Q,
                                                   const u16* __restrict__ Kk,
                                                   const u16* __restrict__ Vp,
                                                   u16* __restrict__ O)
{
    __shared__ u16 Kl[2][64][64];
    __shared__ u16 Vl[2][64][64];

    const int t = threadIdx.x;
    const int w = t >> 6;
    const int lane = t & 63;
    const int lo = lane & 15, hi = lane >> 4;
    const int l8 = lane >> 3, l7 = lane & 7;
    const int bi = blockIdx.x;                  // 0..15
    const int bh = blockIdx.y;
    const int p  = bi + 16 * w;                 // pair 0..63
    const int ql0 = 16 * p;
    const int qh0 = 16 * (127 - p);
    const int NT  = ((2047 - 16 * bi) >> 6) + 1;  // block-uniform tile count

    const u16* Qp = Q  + (size_t)bh * Tc * HDc;
    const u16* Kp = Kk + (size_t)bh * Tc * HDc;
    const u16* Vq = Vp + (size_t)bh * Tc * HDc;   // permuted panel image

    const float sc2 = 0.125f * 1.44269504f;
    const f32x4 fzero = {0.f, 0.f, 0.f, 0.f};

    // Q fragments (B-operand), prescaled into exp2 domain
    bf16x8 qfl[2], qfh[2];
    #pragma unroll
    for (int h = 0; h < 2; ++h) {
        union { bf16x8 v; u16 u[8]; } a2, r2;
        a2.v = *reinterpret_cast<const bf16x8*>(Qp + (ql0 + lo) * HDc + 32 * h + 8 * hi);
        #pragma unroll
        for (int jj = 0; jj < 8; ++jj) {
            union { float f; unsigned u; } cc; cc.u = ((unsigned)a2.u[jj]) << 16;
            r2.u[jj] = f2b(cc.f * sc2);
        }
        qfl[h] = r2.v;
        a2.v = *reinterpret_cast<const bf16x8*>(Qp + (qh0 + lo) * HDc + 32 * h + 8 * hi);
        #pragma unroll
        for (int jj = 0; jj < 8; ++jj) {
            union { float f; unsigned u; } cc; cc.u = ((unsigned)a2.u[jj]) << 16;
            r2.u[jj] = f2b(cc.f * sc2);
        }
        qfh[h] = r2.v;
    }

    f32x4 ol[4], oh[4];
    float ml = -__builtin_inff(), mh = -__builtin_inff();
    float ll = 0.f, lh = 0.f;
    #pragma unroll
    for (int d = 0; d < 4; ++d) { ol[d] = fzero; oh[d] = fzero; }

    // staging: wave w stages rows [16w,16w+16) of each 8KB tile (K and V)
    const int rb = 16 * w;
    const int swz = (l7 ^ l8) * 8;              // pre-swizzled source slot
    auto stage = [&](int tile, int b) {
        const u16* ksrc = Kp + (size_t)(tile * 64 + rb + l8) * 64 + swz;
        const u16* vsrc = Vq + (size_t)(tile * 64 + rb + l8) * 64 + swz;
        gload16(ksrc,          &Kl[b][rb][0]);
        gload16(ksrc + 8 * 64, &Kl[b][rb + 8][0]);
        gload16(vsrc,          &Vl[b][rb][0]);
        gload16(vsrc + 8 * 64, &Vl[b][rb + 8][0]);
    };

    // one 32-key substep for one 16-row q-tile (shfl-free steady state)
    auto step16 = [&](int kb, int q0v, const bf16x8 (&qv)[2], f32x4 (&o)[4],
                      float& m2, float& l2,
                      const bf16x8 (&kf)[2][2], const bf16x8 (&vf)[4]) {
        f32x4 s0, s1;
        s0 = __builtin_amdgcn_mfma_f32_16x16x32_bf16(kf[0][0], qv[0], fzero, 0, 0, 0);
        s0 = __builtin_amdgcn_mfma_f32_16x16x32_bf16(kf[0][1], qv[1], s0, 0, 0, 0);
        s1 = __builtin_amdgcn_mfma_f32_16x16x32_bf16(kf[1][0], qv[0], fzero, 0, 0, 0);
        s1 = __builtin_amdgcn_mfma_f32_16x16x32_bf16(kf[1][1], qv[1], s1, 0, 0, 0);

        if (kb + 31 > q0v) {            // diagonal window: mask keys > q
            const int q = q0v + lo;
            #pragma unroll
            for (int r = 0; r < 4; ++r) {
                if (kb + 4 * hi + r > q)      s0[r] = -__builtin_inff();
                if (kb + 16 + 4 * hi + r > q) s1[r] = -__builtin_inff();
            }
        }

        const float lmax = fmaxf(
            fmaxf(fmaxf(s0[0], s0[1]), fmaxf(s0[2], s0[3])),
            fmaxf(fmaxf(s1[0], s1[1]), fmaxf(s1[2], s1[3])));

        // defer gate: lane-local (conservative: row fail => some lane fails)
        if (!__all(lmax <= m2 + 11.5f)) {   // rescale path (rare)
            float tmx = lmax;
            tmx = fmaxf(tmx, __shfl_xor(tmx, 16));
            tmx = fmaxf(tmx, __shfl_xor(tmx, 32));
            const float mn = fmaxf(m2, tmx);
            const float aq = exp2_hw(m2 - mn);   // -inf -> 0 first time
            m2 = mn;
            l2 *= aq;
            float ar[4];
            #pragma unroll
            for (int r = 0; r < 4; ++r) ar[r] = __shfl(aq, 4 * hi + r);
            #pragma unroll
            for (int d = 0; d < 4; ++d)
                #pragma unroll
                for (int r = 0; r < 4; ++r) o[d][r] *= ar[r];
        }

        float pr[8];
        #pragma unroll
        for (int r = 0; r < 4; ++r) pr[r]     = exp2_hw(s0[r] - m2);
        #pragma unroll
        for (int r = 0; r < 4; ++r) pr[4 + r] = exp2_hw(s1[r] - m2);
        l2 += ((pr[0] + pr[1]) + (pr[2] + pr[3])) + ((pr[4] + pr[5]) + (pr[6] + pr[7]));
        union { bf16x8 v; unsigned wv[4]; } pk;
        pk.wv[0] = cvt_pk(pr[0], pr[1]);
        pk.wv[1] = cvt_pk(pr[2], pr[3]);
        pk.wv[2] = cvt_pk(pr[4], pr[5]);
        pk.wv[3] = cvt_pk(pr[6], pr[7]);
        #pragma unroll
        for (int d = 0; d < 4; ++d)
            o[d] = __builtin_amdgcn_mfma_f32_16x16x32_bf16(pk.v, vf[d], o[d], 0, 0, 0);
    };

    stage(0, 0);
    __syncthreads();

    for (int tt = 0; tt < NT; ++tt) {
        const int cur = tt & 1;
        if (tt + 1 < NT) stage(tt + 1, cur ^ 1);
        const int kb64 = tt << 6;

        #pragma unroll
        for (int p2 = 0; p2 < 2; ++p2) {
            const int kb = kb64 + 32 * p2;
            if (kb > qh0 + 15) break;          // wave done this tile

            const int sw = lo & 7;
            bf16x8 kf[2][2];
            #pragma unroll
            for (int kt = 0; kt < 2; ++kt)
                #pragma unroll
                for (int h = 0; h < 2; ++h)
                    kf[kt][h] = *reinterpret_cast<const bf16x8*>(
                        &Kl[cur][32 * p2 + 16 * kt + lo][((4 * h + hi) ^ sw) * 8]);
            bf16x8 vf[4];
            #pragma unroll
            for (int d = 0; d < 4; ++d)
                vf[d] = *reinterpret_cast<const bf16x8*>(
                    &Vl[cur][16 * d + lo][((4 * p2 + hi) ^ sw) * 8]);

            step16(kb, qh0, qfh, oh, mh, lh, kf, vf);
            if (kb <= ql0 + 15) step16(kb, ql0, qfl, ol, ml, ll, kf, vf);
        }
        __syncthreads();
    }

    // ---- epilogue: reduce lane-local l over hi groups, normalize, write ----
    const int b = bh >> 4, h = bh & 15;
    {
        float lt = ll;
        lt += __shfl_xor(lt, 16);
        lt += __shfl_xor(lt, 32);
        float li[4];
        #pragma unroll
        for (int r = 0; r < 4; ++r) li[r] = 1.0f / __shfl(lt, 4 * hi + r);
        #pragma unroll
        for (int d = 0; d < 4; ++d)
            #pragma unroll
            for (int r = 0; r < 4; ++r) {
                const int q = ql0 + 4 * hi + r;
                O[(size_t)(b * Tc + q) * Dc + h * 64 + 16 * d + lo] = f2b(ol[d][r] * li[r]);
            }
        lt = lh;
        lt += __shfl_xor(lt, 16);
        lt += __shfl_xor(lt, 32);
        #pragma unroll
        for (int r = 0; r < 4; ++r) li[r] = 1.0f / __shfl(lt, 4 * hi + r);
        #pragma unroll
        for (int d = 0; d < 4; ++d)
            #pragma unroll
            for (int r = 0; r < 4; ++r) {
                const int q = qh0 + 4 * hi + r;
                O[(size_t)(b * Tc + q) * Dc + h * 64 + 16 * d + lo] = f2b(oh[d][r] * li[r]);
            }
    }
}

// ---------------- host launcher ----------------
extern "C" void kernel_launch(void* const* d_in, const int* in_sizes, int n_in,
                              void* d_out, int out_size, void* d_ws, size_t ws_size,
                              hipStream_t stream) {
    (void)in_sizes; (void)n_in; (void)out_size; (void)ws_size;
    const float* x  = (const float*)d_in[0];
    const float* Wk = (const float*)d_in[1];
    const float* Wq = (const float*)d_in[2];
    const float* Wv = (const float*)d_in[3];
    const float* Wp = (const float*)d_in[4];
    const float* bp = (const float*)d_in[5];
    float* out = (float*)d_out;

    char* ws = (char*)d_ws;
    u16* xb   = (u16*)(ws);
    u16* wqb  = (u16*)(ws + (8u  << 20));
    u16* wkb  = (u16*)(ws + (10u << 20));
    u16* wvb  = (u16*)(ws + (12u << 20));
    u16* wpb  = (u16*)(ws + (14u << 20));
    u16* Qb   = (u16*)(ws + (16u << 20));
    u16* Kb   = (u16*)(ws + (24u << 20));
    u16* Vtb  = (u16*)(ws + (32u << 20));   // permuted V panels
    u16* attb = (u16*)(ws + (40u << 20));

    CvtArgs ca;
    ca.src[0] = x;  ca.dst[0] = xb;  ca.n[0] = Mg * Dc;
    ca.src[1] = Wq; ca.dst[1] = wqb; ca.n[1] = Dc * Dc;
    ca.src[2] = Wk; ca.dst[2] = wkb; ca.n[2] = Dc * Dc;
    ca.src[3] = Wv; ca.dst[3] = wvb; ca.n[3] = Dc * Dc;
    ca.src[4] = Wp; ca.dst[4] = wpb; ca.n[4] = Dc * Dc;
    cvt_all<<<dim3(1024), 256, 0, stream>>>(ca);

    gemm_bt<0><<<dim3(Dc / 128, Mg / 128, 3), 256, 0, stream>>>(
        xb, wqb, wkb, wvb, Qb, Kb, Vtb, nullptr, nullptr);

    attn_kernel<<<dim3(16, Bc * Hc), 256, 0, stream>>>(Qb, Kb, Vtb, attb);

    gemm_bt<1><<<dim3(Dc / 128, Mg / 128, 1), 256, 0, stream>>>(
        attb, wpb, wpb, wpb, nullptr, nullptr, nullptr, bp, out);
}

// Round 8
// 110.336 us; speedup vs baseline: 2.9137x; 1.1396x over previous
//
#include <hip/hip_runtime.h>

typedef unsigned short u16;
typedef __bf16 bf16;
typedef bf16  bf16x8 __attribute__((ext_vector_type(8)));
typedef float f32x4  __attribute__((ext_vector_type(4)));

constexpr int Bc  = 2;
constexpr int Tc  = 2048;
constexpr int Dc  = 1024;
constexpr int Hc  = 16;
constexpr int HDc = 64;
constexpr int Mg  = Bc * Tc;   // 4096 tokens
constexpr int Kg  = Dc;        // 1024 reduction dim

// round-to-nearest-even f32 -> bf16 (finite inputs only)
__device__ inline u16 f2b(float f) {
    union { float f; unsigned u; } c; c.f = f;
    unsigned r = c.u + 0x7FFFu + ((c.u >> 16) & 1u);
    return (u16)(r >> 16);
}

__device__ inline float exp2_hw(float x) {
    float r; asm("v_exp_f32 %0, %1" : "=v"(r) : "v"(x)); return r;
}
__device__ inline unsigned cvt_pk(float a, float b) {
    unsigned r; asm("v_cvt_pk_bf16_f32 %0, %1, %2" : "=v"(r) : "v"(a), "v"(b)); return r;
}
__device__ inline void gload16(const u16* g, u16* l) {
    __builtin_amdgcn_global_load_lds(
        (const __attribute__((address_space(1))) void*)g,
        (__attribute__((address_space(3))) void*)l, 16, 0, 0);
}

// ---------------- fused fp32 -> bf16 conversion (all 5 tensors, 1 launch) --------
struct CvtArgs { const float* src[5]; u16* dst[5]; int n[5]; };

__global__ __launch_bounds__(256) void cvt_all(CvtArgs a) {
    const int tid = blockIdx.x * blockDim.x + threadIdx.x;
    const int stride = gridDim.x * blockDim.x * 4;
    #pragma unroll
    for (int r = 0; r < 5; ++r) {
        const float* s = a.src[r];
        u16* d = a.dst[r];
        const int n = a.n[r];
        for (int i = tid * 4; i < n; i += stride) {
            float4 v = *reinterpret_cast<const float4*>(s + i);
            ushort4 o;
            o.x = f2b(v.x); o.y = f2b(v.y); o.z = f2b(v.z); o.w = f2b(v.w);
            *reinterpret_cast<ushort4*>(d + i) = o;
        }
    }
}

// ---------------- GEMM: C[M,N] = A[M,K] * W[N,K]^T (m97 structure) ----------------
// EPI==0: z selects {Q,K,V}; Q/K -> [B,H,T,HD]; V -> permuted panel layout
//   Vp[bh][tile=t/64][row=hd][slot 0..7][8 elems]:
//   slot 4*c+s holds keys 64*tile + 32*c + {4s..4s+3, 16+4s..16+4s+3}.
template<int EPI>
__global__ __launch_bounds__(256) void gemm_bt(
    const u16* __restrict__ A,
    const u16* __restrict__ W0, const u16* __restrict__ W1, const u16* __restrict__ W2,
    u16* __restrict__ dQ, u16* __restrict__ dK, u16* __restrict__ dV,
    const float* __restrict__ bias, float* __restrict__ outF)
{
    __shared__ u16 As[128 * 32];
    __shared__ u16 Bs[128 * 32];

    const int t    = threadIdx.x;
    const int z    = blockIdx.z;
    const int m0   = blockIdx.y * 128;
    const int n0   = blockIdx.x * 128;
    const u16* Wsel = (z == 0) ? W0 : (z == 1) ? W1 : W2;

    const int lane = t & 63, wave = t >> 6;
    const int wm = wave >> 1, wn = wave & 1;
    const int lo = lane & 15, hi = lane >> 4;

    f32x4 acc[4][4];
    const f32x4 fzero = {0.f, 0.f, 0.f, 0.f};
    #pragma unroll
    for (int i = 0; i < 4; ++i)
        #pragma unroll
        for (int j = 0; j < 4; ++j) acc[i][j] = fzero;

    const int rA = t >> 2;
    const int ks = ((t & 3) ^ (rA & 3)) * 8;
    const u16* gA0 = A    + (size_t)(m0 + rA) * Kg + ks;
    const u16* gA1 = gA0 + 64 * Kg;
    const u16* gB0 = Wsel + (size_t)(n0 + rA) * Kg + ks;
    const u16* gB1 = gB0 + 64 * Kg;
    u16* lA0 = &As[(wave * 16) * 32];
    u16* lA1 = &As[(64 + wave * 16) * 32];
    u16* lB0 = &Bs[(wave * 16) * 32];
    u16* lB1 = &Bs[(64 + wave * 16) * 32];

    const int sl = (hi ^ (lo & 3)) * 8;

    for (int k0 = 0; k0 < Kg; k0 += 32) {
        __syncthreads();
        gload16(gA0 + k0, lA0);
        gload16(gA1 + k0, lA1);
        gload16(gB0 + k0, lB0);
        gload16(gB1 + k0, lB1);
        __syncthreads();

        bf16x8 af[4], bfr[4];
        #pragma unroll
        for (int fi = 0; fi < 4; ++fi)
            af[fi] = *reinterpret_cast<const bf16x8*>(&As[(wm * 64 + fi * 16 + lo) * 32 + sl]);
        #pragma unroll
        for (int fj = 0; fj < 4; ++fj)
            bfr[fj] = *reinterpret_cast<const bf16x8*>(&Bs[(wn * 64 + fj * 16 + lo) * 32 + sl]);
        #pragma unroll
        for (int fi = 0; fi < 4; ++fi)
            #pragma unroll
            for (int fj = 0; fj < 4; ++fj)
                acc[fi][fj] = __builtin_amdgcn_mfma_f32_16x16x32_bf16(af[fi], bfr[fj], acc[fi][fj], 0, 0, 0);
    }

    #pragma unroll
    for (int fi = 0; fi < 4; ++fi) {
        #pragma unroll
        for (int fj = 0; fj < 4; ++fj) {
            const int nn = n0 + wn * 64 + fj * 16 + lo;
            if constexpr (EPI == 0) {
                const int b = m0 >> 11;
                const int h = nn >> 6, hd = nn & 63;
                if (z == 2) {
                    const int tt0 = (m0 & (Tc - 1)) + wm * 64 + fi * 16 + hi * 4;
                    const int tile = tt0 >> 6;
                    const int k6   = tt0 & 63;
                    const int slot = ((k6 & 32) >> 3) + ((k6 & 15) >> 2);
                    const int halfE = (k6 & 16) >> 2;            // 0 or 4 elems
                    const size_t off =
                        (((size_t)(b * Hc + h) * 32 + tile) * 64 + hd) * 64 + slot * 8 + halfE;
                    ushort4 pv;
                    pv.x = f2b(acc[fi][fj][0]); pv.y = f2b(acc[fi][fj][1]);
                    pv.z = f2b(acc[fi][fj][2]); pv.w = f2b(acc[fi][fj][3]);
                    *reinterpret_cast<ushort4*>(&dV[off]) = pv;
                } else {
                    u16* dst = (z == 0) ? dQ : dK;
                    #pragma unroll
                    for (int r = 0; r < 4; ++r) {
                        const int m = m0 + wm * 64 + fi * 16 + hi * 4 + r;
                        const int tt = m & (Tc - 1);
                        dst[((((b * Hc + h) << 11) + tt) * HDc) + hd] = f2b(acc[fi][fj][r]);
                    }
                }
            } else {
                #pragma unroll
                for (int r = 0; r < 4; ++r) {
                    const int m = m0 + wm * 64 + fi * 16 + hi * 4 + r;
                    outF[(size_t)m * Dc + nn] = acc[fi][fj][r] + bias[nn];
                }
            }
        }
    }
}

// ---------------- causal flash attention: key-parity split + correct merge -------
// Block (bi,bh), bi in 0..15, 512 thr = 8 waves. Wave 2j+c owns 16-row tile pair
// p = bi + 16j (low rows [16p,+16), high rows [16(127-p),+16)) and key PARITY c:
// it processes keys kb = 64*tt + 32*c of each staged 64-key tile. 4096 waves total
// -> 4 waves/SIMD. Per-wave shfl-free online softmax (lane-local gate + lane-local
// l). End: 2-way parity merge via LDS with proper S-domain -> C-domain transpose.
__global__ __launch_bounds__(512, 4) void attn_kernel(const u16* __restrict__ Q,
                                                      const u16* __restrict__ Kk,
                                                      const u16* __restrict__ Vp,
                                                      u16* __restrict__ O)
{
    __shared__ u16 Kl[2][64][64];   // 16 KB
    __shared__ u16 Vl[2][64][64];   // 16 KB
    // merge scratch aliases Kl/Vl (main loop fully done before use)
    float* Ob = (float*)&Kl[0][0][0];   // [4][64][16] floats = 16 KB
    float* Mb = (float*)&Vl[0][0][0];   // [4][16]
    float* Lb = Mb + 64;                // [4][16]

    const int t = threadIdx.x;
    const int w = t >> 6;
    const int lane = t & 63;
    const int j = w >> 1, c = w & 1;
    const int lo = lane & 15, hi = lane >> 4;
    const int l8 = lane >> 3, l7 = lane & 7;
    const int bi = blockIdx.x;                  // 0..15
    const int bh = blockIdx.y;
    const int p  = bi + 16 * j;                 // pair 0..63
    const int ql0 = 16 * p;
    const int qh0 = 16 * (127 - p);
    const int NT  = ((2047 - 16 * bi) >> 6) + 1;  // block-uniform tile count

    const u16* Qp = Q  + (size_t)bh * Tc * HDc;
    const u16* Kp = Kk + (size_t)bh * Tc * HDc;
    const u16* Vq = Vp + (size_t)bh * Tc * HDc;   // permuted panel image

    const float sc2 = 0.125f * 1.44269504f;
    const f32x4 fzero = {0.f, 0.f, 0.f, 0.f};

    // Q fragments (B-operand), prescaled into exp2 domain
    bf16x8 qfl[2], qfh[2];
    #pragma unroll
    for (int h = 0; h < 2; ++h) {
        union { bf16x8 v; u16 u[8]; } a2, r2;
        a2.v = *reinterpret_cast<const bf16x8*>(Qp + (ql0 + lo) * HDc + 32 * h + 8 * hi);
        #pragma unroll
        for (int jj = 0; jj < 8; ++jj) {
            union { float f; unsigned u; } cc; cc.u = ((unsigned)a2.u[jj]) << 16;
            r2.u[jj] = f2b(cc.f * sc2);
        }
        qfl[h] = r2.v;
        a2.v = *reinterpret_cast<const bf16x8*>(Qp + (qh0 + lo) * HDc + 32 * h + 8 * hi);
        #pragma unroll
        for (int jj = 0; jj < 8; ++jj) {
            union { float f; unsigned u; } cc; cc.u = ((unsigned)a2.u[jj]) << 16;
            r2.u[jj] = f2b(cc.f * sc2);
        }
        qfh[h] = r2.v;
    }

    f32x4 ol[4], oh[4];
    float ml = -__builtin_inff(), mh = -__builtin_inff();
    float ll = 0.f, lh = 0.f;
    #pragma unroll
    for (int d = 0; d < 4; ++d) { ol[d] = fzero; oh[d] = fzero; }

    // staging: wave w stages rows [8w,8w+8) of each 8KB tile (1 gload16 K + 1 V)
    const int rb = 8 * w;
    const int swz = (l7 ^ l8) * 8;              // pre-swizzled source slot
    auto stage = [&](int tile, int b) {
        const u16* ksrc = Kp + (size_t)(tile * 64 + rb + l8) * 64 + swz;
        const u16* vsrc = Vq + (size_t)(tile * 64 + rb + l8) * 64 + swz;
        gload16(ksrc, &Kl[b][rb][0]);
        gload16(vsrc, &Vl[b][rb][0]);
    };

    // one 32-key substep for one 16-row q-tile (shfl-free steady state)
    auto step16 = [&](int kb, int q0v, const bf16x8 (&qv)[2], f32x4 (&o)[4],
                      float& m2, float& l2,
                      const bf16x8 (&kf)[2][2], const bf16x8 (&vf)[4]) {
        f32x4 s0, s1;
        s0 = __builtin_amdgcn_mfma_f32_16x16x32_bf16(kf[0][0], qv[0], fzero, 0, 0, 0);
        s0 = __builtin_amdgcn_mfma_f32_16x16x32_bf16(kf[0][1], qv[1], s0, 0, 0, 0);
        s1 = __builtin_amdgcn_mfma_f32_16x16x32_bf16(kf[1][0], qv[0], fzero, 0, 0, 0);
        s1 = __builtin_amdgcn_mfma_f32_16x16x32_bf16(kf[1][1], qv[1], s1, 0, 0, 0);

        if (kb + 31 > q0v) {            // diagonal window: mask keys > q
            const int q = q0v + lo;
            #pragma unroll
            for (int r = 0; r < 4; ++r) {
                if (kb + 4 * hi + r > q)      s0[r] = -__builtin_inff();
                if (kb + 16 + 4 * hi + r > q) s1[r] = -__builtin_inff();
            }
        }

        const float lmax = fmaxf(
            fmaxf(fmaxf(s0[0], s0[1]), fmaxf(s0[2], s0[3])),
            fmaxf(fmaxf(s1[0], s1[1]), fmaxf(s1[2], s1[3])));

        if (!__all(lmax <= m2 + 11.5f)) {   // rescale path (rare)
            float tmx = lmax;
            tmx = fmaxf(tmx, __shfl_xor(tmx, 16));
            tmx = fmaxf(tmx, __shfl_xor(tmx, 32));
            const float mn = fmaxf(m2, tmx);
            const float aq = exp2_hw(m2 - mn);   // -inf -> 0 first time
            m2 = mn;
            l2 *= aq;
            float ar[4];
            #pragma unroll
            for (int r = 0; r < 4; ++r) ar[r] = __shfl(aq, 4 * hi + r);
            #pragma unroll
            for (int d = 0; d < 4; ++d)
                #pragma unroll
                for (int r = 0; r < 4; ++r) o[d][r] *= ar[r];
        }

        float pr[8];
        #pragma unroll
        for (int r = 0; r < 4; ++r) pr[r]     = exp2_hw(s0[r] - m2);
        #pragma unroll
        for (int r = 0; r < 4; ++r) pr[4 + r] = exp2_hw(s1[r] - m2);
        l2 += ((pr[0] + pr[1]) + (pr[2] + pr[3])) + ((pr[4] + pr[5]) + (pr[6] + pr[7]));
        union { bf16x8 v; unsigned wv[4]; } pk;
        pk.wv[0] = cvt_pk(pr[0], pr[1]);
        pk.wv[1] = cvt_pk(pr[2], pr[3]);
        pk.wv[2] = cvt_pk(pr[4], pr[5]);
        pk.wv[3] = cvt_pk(pr[6], pr[7]);
        #pragma unroll
        for (int d = 0; d < 4; ++d)
            o[d] = __builtin_amdgcn_mfma_f32_16x16x32_bf16(pk.v, vf[d], o[d], 0, 0, 0);
    };

    stage(0, 0);
    __syncthreads();

    for (int tt = 0; tt < NT; ++tt) {
        const int cur = tt & 1;
        if (tt + 1 < NT) stage(tt + 1, cur ^ 1);
        const int kb = (tt << 6) + 32 * c;      // this wave's parity half

        const bool hAct = (kb <= qh0 + 15);
        const bool lAct = (kb <= ql0 + 15);
        if (hAct || lAct) {
            const int sw = lo & 7;
            bf16x8 kf[2][2];
            #pragma unroll
            for (int kt = 0; kt < 2; ++kt)
                #pragma unroll
                for (int h = 0; h < 2; ++h)
                    kf[kt][h] = *reinterpret_cast<const bf16x8*>(
                        &Kl[cur][32 * c + 16 * kt + lo][((4 * h + hi) ^ sw) * 8]);
            bf16x8 vf[4];
            #pragma unroll
            for (int d = 0; d < 4; ++d)
                vf[d] = *reinterpret_cast<const bf16x8*>(
                    &Vl[cur][16 * d + lo][((4 * c + hi) ^ sw) * 8]);

            if (hAct) step16(kb, qh0, qfh, oh, mh, lh, kf, vf);
            if (lAct) step16(kb, ql0, qfl, ol, ml, ll, kf, vf);
        }
        __syncthreads();
    }

    // ---- parity merge (correct domains) + output: high tile then low tile ----
    const int b = bh >> 4, h = bh & 15;
    #pragma unroll
    for (int ph = 0; ph < 2; ++ph) {
        const f32x4* om = (ph == 0) ? oh : ol;          // my fragments
        const float  mm = (ph == 0) ? mh : ml;
        const float  lm = (ph == 0) ? lh : ll;
        const int    q0 = (ph == 0) ? qh0 : ql0;

        if (c == 1) {
            float lt = lm;                               // row-reduce partial l
            lt += __shfl_xor(lt, 16);
            lt += __shfl_xor(lt, 32);
            if (hi == 0) { Mb[j * 16 + lo] = mm; Lb[j * 16 + lo] = lt; }
            float* op = Ob + (j * 64 + lane) * 16;
            #pragma unroll
            for (int d = 0; d < 4; ++d)
                #pragma unroll
                for (int r = 0; r < 4; ++r) op[d * 4 + r] = om[d][r];
        }
        __syncthreads();
        if (c == 0) {
            float lt = lm;                               // my row l (indexed lo)
            lt += __shfl_xor(lt, 16);
            lt += __shfl_xor(lt, 32);
            const float m1 = Mb[j * 16 + lo];
            const float l1 = Lb[j * 16 + lo];
            const float M  = fmaxf(mm, m1);
            const float e0 = exp2_hw(mm - M);            // -inf-safe (mm finite)
            const float e1 = exp2_hw(m1 - M);            // m1 may be -inf -> 0
            const float Li = 1.0f / (lt * e0 + l1 * e1);
            float e0r[4], e1r[4], Lir[4];                // transpose S-row -> C-row
            #pragma unroll
            for (int r = 0; r < 4; ++r) {
                e0r[r] = __shfl(e0, 4 * hi + r);
                e1r[r] = __shfl(e1, 4 * hi + r);
                Lir[r] = __shfl(Li, 4 * hi + r);
            }
            const float* op = Ob + (j * 64 + lane) * 16;
            #pragma unroll
            for (int d = 0; d < 4; ++d)
                #pragma unroll
                for (int r = 0; r < 4; ++r) {
                    const int q = q0 + 4 * hi + r;
                    const float val = (om[d][r] * e0r[r] + op[d * 4 + r] * e1r[r]) * Lir[r];
                    O[(size_t)(b * Tc + q) * Dc + h * 64 + 16 * d + lo] = f2b(val);
                }
        }
        __syncthreads();
    }
}

// ---------------- host launcher ----------------
extern "C" void kernel_launch(void* const* d_in, const int* in_sizes, int n_in,
                              void* d_out, int out_size, void* d_ws, size_t ws_size,
                              hipStream_t stream) {
    (void)in_sizes; (void)n_in; (void)out_size; (void)ws_size;
    const float* x  = (const float*)d_in[0];
    const float* Wk = (const float*)d_in[1];
    const float* Wq = (const float*)d_in[2];
    const float* Wv = (const float*)d_in[3];
    const float* Wp = (const float*)d_in[4];
    const float* bp = (const float*)d_in[5];
    float* out = (float*)d_out;

    char* ws = (char*)d_ws;
    u16* xb   = (u16*)(ws);
    u16* wqb  = (u16*)(ws + (8u  << 20));
    u16* wkb  = (u16*)(ws + (10u << 20));
    u16* wvb  = (u16*)(ws + (12u << 20));
    u16* wpb  = (u16*)(ws + (14u << 20));
    u16* Qb   = (u16*)(ws + (16u << 20));
    u16* Kb   = (u16*)(ws + (24u << 20));
    u16* Vtb  = (u16*)(ws + (32u << 20));   // permuted V panels
    u16* attb = (u16*)(ws + (40u << 20));

    CvtArgs ca;
    ca.src[0] = x;  ca.dst[0] = xb;  ca.n[0] = Mg * Dc;
    ca.src[1] = Wq; ca.dst[1] = wqb; ca.n[1] = Dc * Dc;
    ca.src[2] = Wk; ca.dst[2] = wkb; ca.n[2] = Dc * Dc;
    ca.src[3] = Wv; ca.dst[3] = wvb; ca.n[3] = Dc * Dc;
    ca.src[4] = Wp; ca.dst[4] = wpb; ca.n[4] = Dc * Dc;
    cvt_all<<<dim3(1024), 256, 0, stream>>>(ca);

    gemm_bt<0><<<dim3(Dc / 128, Mg / 128, 3), 256, 0, stream>>>(
        xb, wqb, wkb, wvb, Qb, Kb, Vtb, nullptr, nullptr);

    attn_kernel<<<dim3(16, Bc * Hc), 512, 0, stream>>>(Qb, Kb, Vtb, attb);

    gemm_bt<1><<<dim3(Dc / 128, Mg / 128, 1), 256, 0, stream>>>(
        attb, wpb, wpb, wpb, nullptr, nullptr, nullptr, bp, out);
}